// Round 11
// baseline (488.959 us; speedup 1.0000x reference)
//
#include <hip/hip_runtime.h>
#include <stdint.h>

#define DEV __device__ __forceinline__
typedef unsigned short u16;
typedef __attribute__((ext_vector_type(8))) short bf16x8;
typedef __attribute__((ext_vector_type(4))) float f32x4;

#define AS1 __attribute__((address_space(1)))
#define AS3 __attribute__((address_space(3)))
#define WAITVM0 asm volatile("s_waitcnt vmcnt(0)" ::: "memory")
// scores pre-scaled by 1/sqrt(64) * log2(e) inside the Q-projection epilogue
#define QSCALE 0.18033688011112042f

DEV u16 f2bf(float f) {
  union { float f; uint32_t u; } x; x.f = f;
  uint32_t r = x.u + 0x7fffu + ((x.u >> 16) & 1u);
  return (u16)(r >> 16);
}

DEV uint32_t cvt_pk_bf16(float a, float b) {
  uint32_t r;
  asm("v_cvt_pk_bf16_f32 %0, %1, %2" : "=v"(r) : "v"(a), "v"(b));
  return r;
}

// ---------------- f32 -> bf16 convert, two tensors in one launch ----------------
__global__ __launch_bounds__(256) void k_cvt2(const float* __restrict__ a, const float* __restrict__ bsrc,
                                              u16* __restrict__ oa, u16* __restrict__ ob, int n4) {
  int i = blockIdx.x * blockDim.x + threadIdx.x;
  const float* s;
  u16* o;
  int k;
  if (i < n4) { s = a; o = oa; k = i; }
  else        { s = bsrc; o = ob; k = i - n4; }
  float4 v = reinterpret_cast<const float4*>(s)[k];
  reinterpret_cast<ushort4*>(o)[k] = make_ushort4(f2bf(v.x), f2bf(v.y), f2bf(v.z), f2bf(v.w));
}

// ---------------- batched weight transpose+convert: W f32 [K][M] -> WT bf16 [M][K] ----------------
struct WTJob { const float* W; u16* WT; int K, M, msh, start; };
struct WTJobs { WTJob j[12]; };

__global__ void k_wT_all(WTJobs jobs) {
  __shared__ float tile[32][33];
  int b = blockIdx.x;
  int i = 0;
#pragma unroll
  for (int t = 1; t < 12; ++t)
    if (b >= jobs.j[t].start) i = t;
  const WTJob J = jobs.j[i];
  int rel = b - J.start;
  int m0 = (rel & ((1 << J.msh) - 1)) << 5;
  int k0 = (rel >> J.msh) << 5;
  int tx = threadIdx.x, ty = threadIdx.y;  // (32,8)
#pragma unroll
  for (int q = 0; q < 4; ++q)
    tile[ty + q * 8][tx] = J.W[(size_t)(k0 + ty + q * 8) * J.M + m0 + tx];
  __syncthreads();
#pragma unroll
  for (int q = 0; q < 4; ++q)
    J.WT[(size_t)(m0 + ty + q * 8) * J.K + k0 + tx] = f2bf(tile[tx][ty + q * 8]);
}

// ---- global->LDS staging of an R x 64 bf16 tile (128B rows), 256 threads ----
template<int R>
DEV void stage_tile(const u16* __restrict__ g, int strideElems, u16* lds, int tid, int wv) {
#pragma unroll
  for (int t = 0; t < R / 32; ++t) {
    int idx = t * 256 + tid;
    int row = idx >> 3;
    int b = (idx & 7) << 4;
    int sb = b ^ ((row & 7) << 4);
    const char* src = (const char*)g + (size_t)row * strideElems * 2 + sb;
    char* dst = (char*)lds + (size_t)(t * 256 + wv * 64) * 16;  // wave-uniform; HW adds lane*16
    __builtin_amdgcn_global_load_lds((const AS1 void*)src, (AS3 void*)dst, 16, 0, 0);
  }
}

// ---- global->LDS staging of a 128 x 64 bf16 tile, 128 threads ----
DEV void stage128(const u16* __restrict__ g, int strideElems, u16* lds, int tid, int wv) {
#pragma unroll
  for (int t = 0; t < 8; ++t) {
    int idx = t * 128 + tid;
    int row = idx >> 3;
    int b = (idx & 7) << 4;
    int sb = b ^ ((row & 7) << 4);
    const char* src = (const char*)g + (size_t)row * strideElems * 2 + sb;
    char* dst = (char*)lds + (size_t)(t * 128 + wv * 64) * 16;  // wave-uniform; HW adds lane*16
    __builtin_amdgcn_global_load_lds((const AS1 void*)src, (AS3 void*)dst, 16, 0, 0);
  }
}

// swizzled b128 fragment read from a 64-col bf16 tile
DEV bf16x8 lds_frag(const u16* lds, int row, int kel) {
  int off = row * 128 + ((kel * 2) ^ ((row & 7) << 4));
  return *(const bf16x8*)((const char*)lds + off);
}

// ---------------- GEMM: C[n][m] = A[n][:] . WT[m][:] + bias[m] ----------------
// 128xBN (BN=JT*32), BK=64, 4 waves, 2-stage dbuf, XCD-aware bijective swizzle.
// (Proven R8 config for N=1024 GEMMs.) MODE: 0=f32 out, 2=bf16 relu out
template<int JT, int MODE>
__global__ __launch_bounds__(256) void k_gemm(const u16* __restrict__ A, int lda,
                                              const u16* __restrict__ BT,
                                              const float* __restrict__ bias,
                                              void* __restrict__ C, int ldc, int K) {
  constexpr int BN = JT * 32;
  __shared__ __align__(16) u16 A_lds[2][128 * 64];
  __shared__ __align__(16) u16 B_lds[2][BN * 64];
  const int tid = threadIdx.x, lane = tid & 63, wv = tid >> 6;
  const int wm = wv >> 1, wn = wv & 1;
  const int nwg = gridDim.x * gridDim.y;
  const int flat = blockIdx.y * gridDim.x + blockIdx.x;
  const int sw = (flat & 7) * (nwg >> 3) + (flat >> 3);
  const int bx = sw % gridDim.x, by = sw / gridDim.x;
  const int bm0 = by * 128, bn0 = bx * BN;
  const int lr = lane & 15, lk = (lane >> 4) * 8, r0 = (lane >> 4) * 4;

  f32x4 acc[4][JT];
#pragma unroll
  for (int i = 0; i < 4; ++i)
#pragma unroll
    for (int j = 0; j < JT; ++j) acc[i][j] = f32x4{0.f, 0.f, 0.f, 0.f};

  stage_tile<128>(A + (size_t)bm0 * lda, lda, A_lds[0], tid, wv);
  stage_tile<BN>(BT + (size_t)bn0 * K, K, B_lds[0], tid, wv);
  WAITVM0;
  __builtin_amdgcn_s_barrier();

  int cur = 0;
  for (int k0 = 0; k0 < K; k0 += 64) {
    if (k0 + 64 < K) {
      stage_tile<128>(A + (size_t)bm0 * lda + k0 + 64, lda, A_lds[cur ^ 1], tid, wv);
      stage_tile<BN>(BT + (size_t)bn0 * K + k0 + 64, K, B_lds[cur ^ 1], tid, wv);
    }
#pragma unroll
    for (int kk = 0; kk < 2; ++kk) {
      bf16x8 af[4], bfr[JT];
#pragma unroll
      for (int i = 0; i < 4; ++i) af[i] = lds_frag(A_lds[cur], wm * 64 + i * 16 + lr, kk * 32 + lk);
#pragma unroll
      for (int j = 0; j < JT; ++j) bfr[j] = lds_frag(B_lds[cur], wn * (JT * 16) + j * 16 + lr, kk * 32 + lk);
#pragma unroll
      for (int i = 0; i < 4; ++i)
#pragma unroll
        for (int j = 0; j < JT; ++j)
          acc[i][j] = __builtin_amdgcn_mfma_f32_16x16x32_bf16(af[i], bfr[j], acc[i][j], 0, 0, 0);
    }
    WAITVM0;
    __builtin_amdgcn_s_barrier();
    cur ^= 1;
  }

#pragma unroll
  for (int j = 0; j < JT; ++j) {
    int col = bn0 + wn * (JT * 16) + j * 16 + lr;
    float bv = bias[col];
#pragma unroll
    for (int i = 0; i < 4; ++i) {
      int rowb = bm0 + wm * 64 + i * 16 + r0;
      if constexpr (MODE == 0) {
#pragma unroll
        for (int r = 0; r < 4; ++r)
          ((float*)C)[(size_t)(rowb + r) * ldc + col] = acc[i][j][r] + bv;
      } else {
#pragma unroll
        for (int r = 0; r < 4; ++r) {
          float v = fmaxf(acc[i][j][r] + bv, 0.f);
          ((u16*)C)[(size_t)(rowb + r) * ldc + col] = f2bf(v);
        }
      }
    }
  }
}

// ---------------- wide-N GEMM: 2 waves, 128x128 tile, wave owns 128x64 output ----------------
// FLOP:LDS-read ratio 43.7K/read (2x the 4-wave 64x32-per-wave config) -- attacks the
// measured LDS-throughput bound (~85 B/cy/CU). LDS 64KB dbuf -> 2 blocks/CU.
// MODE: 2=bf16 relu out (FFN1)
template<int MODE>
__global__ __launch_bounds__(128) void k_gemm2(const u16* __restrict__ A, int lda,
                                               const u16* __restrict__ BT,
                                               const float* __restrict__ bias,
                                               void* __restrict__ C, int ldc, int K) {
  __shared__ __align__(16) u16 A_lds[2][128 * 64];
  __shared__ __align__(16) u16 B_lds[2][128 * 64];
  const int tid = threadIdx.x, lane = tid & 63, wv = tid >> 6;
  const int nwg = gridDim.x * gridDim.y;
  const int flat = blockIdx.y * gridDim.x + blockIdx.x;
  const int sw = (flat & 7) * (nwg >> 3) + (flat >> 3);
  const int bx = sw % gridDim.x, by = sw / gridDim.x;
  const int bm0 = by * 128, bn0 = bx * 128;
  const int lr = lane & 15, lk = (lane >> 4) * 8, r0 = (lane >> 4) * 4;

  f32x4 acc[8][4];
#pragma unroll
  for (int i = 0; i < 8; ++i)
#pragma unroll
    for (int j = 0; j < 4; ++j) acc[i][j] = f32x4{0.f, 0.f, 0.f, 0.f};

  stage128(A + (size_t)bm0 * lda, lda, A_lds[0], tid, wv);
  stage128(BT + (size_t)bn0 * K, K, B_lds[0], tid, wv);
  WAITVM0;
  __builtin_amdgcn_s_barrier();

  int cur = 0;
  for (int k0 = 0; k0 < K; k0 += 64) {
    if (k0 + 64 < K) {
      stage128(A + (size_t)bm0 * lda + k0 + 64, lda, A_lds[cur ^ 1], tid, wv);
      stage128(BT + (size_t)bn0 * K + k0 + 64, K, B_lds[cur ^ 1], tid, wv);
    }
#pragma unroll
    for (int kk = 0; kk < 2; ++kk) {
      bf16x8 af[8], bfr[4];
#pragma unroll
      for (int i = 0; i < 8; ++i) af[i] = lds_frag(A_lds[cur], i * 16 + lr, kk * 32 + lk);
#pragma unroll
      for (int j = 0; j < 4; ++j) bfr[j] = lds_frag(B_lds[cur], wv * 64 + j * 16 + lr, kk * 32 + lk);
#pragma unroll
      for (int i = 0; i < 8; ++i)
#pragma unroll
        for (int j = 0; j < 4; ++j)
          acc[i][j] = __builtin_amdgcn_mfma_f32_16x16x32_bf16(af[i], bfr[j], acc[i][j], 0, 0, 0);
    }
    WAITVM0;
    __builtin_amdgcn_s_barrier();
    cur ^= 1;
  }

#pragma unroll
  for (int j = 0; j < 4; ++j) {
    int col = bn0 + wv * 64 + j * 16 + lr;
    float bv = bias[col];
#pragma unroll
    for (int i = 0; i < 8; ++i) {
      int rowb = bm0 + i * 16 + r0;
      if constexpr (MODE == 0) {
#pragma unroll
        for (int r = 0; r < 4; ++r)
          ((float*)C)[(size_t)(rowb + r) * ldc + col] = acc[i][j][r] + bv;
      } else {
#pragma unroll
        for (int r = 0; r < 4; ++r) {
          float v = fmaxf(acc[i][j][r] + bv, 0.f);
          ((u16*)C)[(size_t)(rowb + r) * ldc + col] = f2bf(v);
        }
      }
    }
  }
}

// ---------------- fused QKV projection: 2-wave 128x128 tiles, N=3072 segments Q|K|V ----------------
__global__ __launch_bounds__(128) void k_qkv2(const u16* __restrict__ Aq, const u16* __restrict__ Akv,
                                              const u16* __restrict__ BT,
                                              const float* __restrict__ bq, const float* __restrict__ bk,
                                              const float* __restrict__ bv,
                                              u16* __restrict__ Qb, u16* __restrict__ Kb,
                                              u16* __restrict__ Vt, int K) {
  __shared__ __align__(16) u16 A_lds[2][128 * 64];
  __shared__ __align__(16) u16 B_lds[2][128 * 64];
  const int tid = threadIdx.x, lane = tid & 63, wv = tid >> 6;
  const int nwg = gridDim.x * gridDim.y;
  const int flat = blockIdx.y * gridDim.x + blockIdx.x;
  const int sw = (flat & 7) * (nwg >> 3) + (flat >> 3);
  const int bx = sw % gridDim.x, by = sw / gridDim.x;
  const int bm0 = by * 128, bn0 = bx * 128;
  const int seg = bn0 >> 10;
  const u16* A = (seg == 0) ? Aq : Akv;
  const int lr = lane & 15, lk = (lane >> 4) * 8, r0 = (lane >> 4) * 4;

  f32x4 acc[8][4];
#pragma unroll
  for (int i = 0; i < 8; ++i)
#pragma unroll
    for (int j = 0; j < 4; ++j) acc[i][j] = f32x4{0.f, 0.f, 0.f, 0.f};

  stage128(A + (size_t)bm0 * K, K, A_lds[0], tid, wv);
  stage128(BT + (size_t)bn0 * K, K, B_lds[0], tid, wv);
  WAITVM0;
  __builtin_amdgcn_s_barrier();

  int cur = 0;
  for (int k0 = 0; k0 < K; k0 += 64) {
    if (k0 + 64 < K) {
      stage128(A + (size_t)bm0 * K + k0 + 64, K, A_lds[cur ^ 1], tid, wv);
      stage128(BT + (size_t)bn0 * K + k0 + 64, K, B_lds[cur ^ 1], tid, wv);
    }
#pragma unroll
    for (int kk = 0; kk < 2; ++kk) {
      bf16x8 af[8], bfr[4];
#pragma unroll
      for (int i = 0; i < 8; ++i) af[i] = lds_frag(A_lds[cur], i * 16 + lr, kk * 32 + lk);
#pragma unroll
      for (int j = 0; j < 4; ++j) bfr[j] = lds_frag(B_lds[cur], wv * 64 + j * 16 + lr, kk * 32 + lk);
#pragma unroll
      for (int i = 0; i < 8; ++i)
#pragma unroll
        for (int j = 0; j < 4; ++j)
          acc[i][j] = __builtin_amdgcn_mfma_f32_16x16x32_bf16(af[i], bfr[j], acc[i][j], 0, 0, 0);
    }
    WAITVM0;
    __builtin_amdgcn_s_barrier();
    cur ^= 1;
  }

#pragma unroll
  for (int j = 0; j < 4; ++j) {
    int col = bn0 + wv * 64 + j * 16 + lr;
    int cl = col & 1023;
#pragma unroll
    for (int i = 0; i < 8; ++i) {
      int rowb = bm0 + i * 16 + r0;
      if (seg == 0) {
        float bb = bq[cl];
#pragma unroll
        for (int r = 0; r < 4; ++r)
          Qb[(size_t)(rowb + r) * 1024 + cl] = f2bf((acc[i][j][r] + bb) * QSCALE);
      } else if (seg == 1) {
        float bb = bk[cl];
#pragma unroll
        for (int r = 0; r < 4; ++r)
          Kb[(size_t)(rowb + r) * 1024 + cl] = f2bf(acc[i][j][r] + bb);
      } else {
        float bb = bv[cl];
        int bidx = rowb >> 11, t = rowb & 2047;
        ushort4 o = make_ushort4(f2bf(acc[i][j][0] + bb), f2bf(acc[i][j][1] + bb),
                                 f2bf(acc[i][j][2] + bb), f2bf(acc[i][j][3] + bb));
        *reinterpret_cast<ushort4*>(&Vt[((size_t)bidx * 1024 + cl) * 2048 + t]) = o;
      }
    }
  }
}

// ---------------- fused residual LayerNorm (row=1024), dual f32/bf16 out ----------------
__global__ __launch_bounds__(256) void k_ln(const float* __restrict__ Rm, const float* __restrict__ X,
                                            const float* __restrict__ g, const float* __restrict__ be,
                                            float* __restrict__ Y, u16* __restrict__ Yb) {
  int row = blockIdx.x;
  size_t base4 = (size_t)row * 256;
  int t = threadIdx.x;
  float4 a = reinterpret_cast<const float4*>(Rm)[base4 + t];
  float4 x = reinterpret_cast<const float4*>(X)[base4 + t];
  float v0 = a.x + x.x, v1 = a.y + x.y, v2 = a.z + x.z, v3 = a.w + x.w;
  float s = v0 + v1 + v2 + v3;
  float ss = v0 * v0 + v1 * v1 + v2 * v2 + v3 * v3;
#pragma unroll
  for (int m = 1; m < 64; m <<= 1) { s += __shfl_xor(s, m); ss += __shfl_xor(ss, m); }
  __shared__ float red[8];
  int wv = t >> 6;
  if ((t & 63) == 0) { red[wv] = s; red[4 + wv] = ss; }
  __syncthreads();
  s = red[0] + red[1] + red[2] + red[3];
  ss = red[4] + red[5] + red[6] + red[7];
  float mean = s * (1.f / 1024.f);
  float var = ss * (1.f / 1024.f) - mean * mean;
  float rstd = rsqrtf(var + 1e-5f);
  float4 gv = reinterpret_cast<const float4*>(g)[t];
  float4 bv = reinterpret_cast<const float4*>(be)[t];
  float o0 = (v0 - mean) * rstd * gv.x + bv.x;
  float o1 = (v1 - mean) * rstd * gv.y + bv.y;
  float o2 = (v2 - mean) * rstd * gv.z + bv.z;
  float o3 = (v3 - mean) * rstd * gv.w + bv.w;
  reinterpret_cast<float4*>(Y)[base4 + t] = make_float4(o0, o1, o2, o3);
  if (Yb) {
    ushort4 ob = make_ushort4(f2bf(o0), f2bf(o1), f2bf(o2), f2bf(o3));
    reinterpret_cast<ushort4*>(Yb)[base4 + t] = ob;
  }
}

// ---------------- flash attention: 8 waves, QBLK=128, 3-buffer ring, counted vmcnt ----------------
// (round-8 proven config: 70us.) Causal: KV-split-2 with f32 partials.
template<bool CAUSAL>
__global__ __launch_bounds__(512) void k_attn(const u16* __restrict__ Q, const u16* __restrict__ Kg,
                                              const u16* __restrict__ Vt, u16* __restrict__ O,
                                              float* __restrict__ OP0, float* __restrict__ OP1,
                                              float* __restrict__ L0, float* __restrict__ L1, int T) {
  __shared__ __align__(16) u16 K_lds[3][64 * 64];
  __shared__ __align__(16) u16 V_lds[3][64 * 64];   // V^T tiles: [dh][kv]
  __shared__ __align__(16) u16 p_lds[8][16 * 64];   // per-wave P rows, swizzled
  const int tid = threadIdx.x, lane = tid & 63, wv = tid >> 6;
  const int h = blockIdx.y, b = blockIdx.z;
  const int lq = lane & 15, g = lane >> 4;
  const int swz = (lq & 7) << 4;
  const int fb0 = lq * 128 + ((g * 16) ^ swz);
  const int fb1 = lq * 128 + ((g * 16 + 64) ^ swz);
  const size_t qkbase = ((size_t)b * T) * 1024 + h * 64;
  const size_t vbase = ((size_t)b * 1024 + h * 64) * T;

  int qx, st, en;
  if constexpr (CAUSAL) {
    qx = 15 - (blockIdx.x >> 1);               // heavy q-tiles dispatch first
    const int s = blockIdx.x & 1;
    const int ntf = 2 * qx + 2, half = qx + 1;
    st = s ? half : 0;
    en = s ? ntf : half;
  } else {
    qx = blockIdx.x;
    st = 0;
    en = T >> 6;
  }
  const int qw = qx * 128 + wv * 16;
  const int dtile = qw >> 6;                    // this wave's diagonal kv-tile

  bf16x8 aq0, aq1;
  {
    const u16* qp_ = Q + qkbase + (size_t)(qw + lq) * 1024 + g * 8;
    aq0 = *reinterpret_cast<const bf16x8*>(qp_);
    aq1 = *reinterpret_cast<const bf16x8*>(qp_ + 32);
  }

  // staging: 512 threads, 1 K-load + 1 V-load each (16B), pre-swizzled source
  const int srow = tid >> 3;
  const int ssb = ((tid & 7) << 4) ^ ((srow & 7) << 4);
  const char* ksrc = (const char*)(Kg + qkbase) + (size_t)srow * 2048 + ssb + (size_t)st * 131072;
  const char* vsrc = (const char*)(Vt + vbase) + (size_t)srow * ((size_t)T * 2) + ssb + (size_t)st * 128;
  const uint32_t doff = (uint32_t)(wv << 10);   // wave-uniform LDS base; HW adds lane*16

  auto stage = [&](int buf) {
    __builtin_amdgcn_global_load_lds((const AS1 void*)ksrc, (AS3 void*)((char*)K_lds[buf] + doff), 16, 0, 0);
    __builtin_amdgcn_global_load_lds((const AS1 void*)vsrc, (AS3 void*)((char*)V_lds[buf] + doff), 16, 0, 0);
    ksrc += 131072;   // 64 rows * 2048B
    vsrc += 128;      // 64 kv cols * 2B
  };

  f32x4 acc[4];
  float lsum = 0.f;
#pragma unroll
  for (int j = 0; j < 4; ++j) acc[j] = f32x4{0.f, 0.f, 0.f, 0.f};

  char* pw = (char*)p_lds[wv];

  auto qstep = [&](bool domask, int kv0, const char* kb, const char* vb) {
    f32x4 st_[4];
    __builtin_amdgcn_s_setprio(1);
#pragma unroll
    for (int j = 0; j < 4; ++j) {
      bf16x8 bk0 = *reinterpret_cast<const bf16x8*>(kb + fb0 + j * 2048);
      bf16x8 bk1 = *reinterpret_cast<const bf16x8*>(kb + fb1 + j * 2048);
      f32x4 t0 = f32x4{0.f, 0.f, 0.f, 0.f};
      t0 = __builtin_amdgcn_mfma_f32_16x16x32_bf16(bk0, aq0, t0, 0, 0, 0);
      t0 = __builtin_amdgcn_mfma_f32_16x16x32_bf16(bk1, aq1, t0, 0, 0, 0);
      st_[j] = t0;
    }
    __builtin_amdgcn_s_setprio(0);
    uint32_t pk[8];
    if (domask) {
      const int qrow = qw + lq;
#pragma unroll
      for (int j = 0; j < 4; ++j) {
        float p0 = __builtin_exp2f(st_[j][0]);
        float p1 = __builtin_exp2f(st_[j][1]);
        float p2 = __builtin_exp2f(st_[j][2]);
        float p3 = __builtin_exp2f(st_[j][3]);
        int kvb = kv0 + j * 16 + g * 4;
        p0 = (kvb > qrow) ? 0.f : p0;
        p1 = (kvb + 1 > qrow) ? 0.f : p1;
        p2 = (kvb + 2 > qrow) ? 0.f : p2;
        p3 = (kvb + 3 > qrow) ? 0.f : p3;
        lsum += (p0 + p1) + (p2 + p3);
        pk[2 * j] = cvt_pk_bf16(p0, p1);
        pk[2 * j + 1] = cvt_pk_bf16(p2, p3);
      }
    } else {
#pragma unroll
      for (int j = 0; j < 4; ++j) {
        float p0 = __builtin_exp2f(st_[j][0]);
        float p1 = __builtin_exp2f(st_[j][1]);
        float p2 = __builtin_exp2f(st_[j][2]);
        float p3 = __builtin_exp2f(st_[j][3]);
        lsum += (p0 + p1) + (p2 + p3);
        pk[2 * j] = cvt_pk_bf16(p0, p1);
        pk[2 * j + 1] = cvt_pk_bf16(p2, p3);
      }
    }
#pragma unroll
    for (int j = 0; j < 4; ++j)
      *reinterpret_cast<uint2*>(pw + lq * 128 + ((j * 32 + g * 8) ^ swz)) =
          make_uint2(pk[2 * j], pk[2 * j + 1]);
    bf16x8 pf0 = *reinterpret_cast<const bf16x8*>(pw + fb0);
    bf16x8 pf1 = *reinterpret_cast<const bf16x8*>(pw + fb1);
    __builtin_amdgcn_s_setprio(1);
#pragma unroll
    for (int j2 = 0; j2 < 4; ++j2) {
      bf16x8 v0 = *reinterpret_cast<const bf16x8*>(vb + fb0 + j2 * 2048);
      bf16x8 v1 = *reinterpret_cast<const bf16x8*>(vb + fb1 + j2 * 2048);
      acc[j2] = __builtin_amdgcn_mfma_f32_16x16x32_bf16(v0, pf0, acc[j2], 0, 0, 0);
      acc[j2] = __builtin_amdgcn_mfma_f32_16x16x32_bf16(v1, pf1, acc[j2], 0, 0, 0);
    }
    __builtin_amdgcn_s_setprio(0);
  };

  // prologue: fill ring with tiles st, st+1
  stage(0);
  if (st + 1 < en) {
    stage(1);
    asm volatile("s_waitcnt vmcnt(2)" ::: "memory");   // tile st done; st+1 in flight
  } else {
    WAITVM0;
  }
  __builtin_amdgcn_s_barrier();

  for (int it = st; it < en; ++it) {
    const int idx = it - st;
    if (it + 2 < en) stage((idx + 2) % 3);
    const char* kb = (const char*)K_lds[idx % 3];
    const char* vb = (const char*)V_lds[idx % 3];
    if (!CAUSAL || it <= dtile)                        // wave-uniform skip of masked tiles
      qstep(CAUSAL && it == dtile, it << 6, kb, vb);
    if (it + 2 < en) {
      asm volatile("s_waitcnt vmcnt(2)" ::: "memory"); // tile it+1 done; it+2 in flight
    } else {
      WAITVM0;
    }
    __builtin_amdgcn_s_barrier();
  }

  lsum += __shfl_xor(lsum, 16);
  lsum += __shfl_xor(lsum, 32);
  if constexpr (CAUSAL) {
    float* OP = (blockIdx.x & 1) ? OP1 : OP0;
    float* Lp = (blockIdx.x & 1) ? L1 : L0;
    const int row = (b * 16 + h) * 2048 + qw + lq;
    float* pr = OP + (size_t)row * 64;
#pragma unroll
    for (int j2 = 0; j2 < 4; ++j2)
      *reinterpret_cast<f32x4*>(pr + j2 * 16 + g * 4) = acc[j2];
    if (g == 0) Lp[row] = lsum;
  } else {
    float inv = 1.f / lsum;
    size_t rb = qkbase + (size_t)(qw + lq) * 1024;
#pragma unroll
    for (int j2 = 0; j2 < 4; ++j2) {
      ushort4 o = make_ushort4(f2bf(acc[j2][0] * inv), f2bf(acc[j2][1] * inv),
                               f2bf(acc[j2][2] * inv), f2bf(acc[j2][3] * inv));
      *reinterpret_cast<ushort4*>(&O[rb + j2 * 16 + g * 4]) = o;
    }
  }
}

// ---------------- split-K attention merge: O = (O0+O1)/(l0+l1), f32 -> bf16 [b][q][h*64+dh] ----------------
__global__ __launch_bounds__(256) void k_amrg(const float* __restrict__ P0, const float* __restrict__ P1,
                                              const float* __restrict__ L0, const float* __restrict__ L1,
                                              u16* __restrict__ Ab) {
  int i = blockIdx.x * 256 + threadIdx.x;   // 1M threads: [2][16][2048] rows x 16 f32x4
  int row = i >> 4, d4 = (i & 15) << 2;
  f32x4 a = *reinterpret_cast<const f32x4*>(&P0[(size_t)row * 64 + d4]);
  f32x4 c = *reinterpret_cast<const f32x4*>(&P1[(size_t)row * 64 + d4]);
  float inv = 1.f / (L0[row] + L1[row]);
  int bh = row >> 11, q = row & 2047, bb = bh >> 4, hh = bh & 15;
  size_t dst = ((size_t)(bb * 2048 + q)) * 1024 + hh * 64 + d4;
  ushort4 o = make_ushort4(f2bf((a[0] + c[0]) * inv), f2bf((a[1] + c[1]) * inv),
                           f2bf((a[2] + c[2]) * inv), f2bf((a[3] + c[3]) * inv));
  *reinterpret_cast<ushort4*>(&Ab[dst]) = o;
}

// ---------------- host orchestration ----------------
extern "C" void kernel_launch(void* const* d_in, const int* in_sizes, int n_in,
                              void* d_out, int out_size, void* d_ws, size_t ws_size,
                              hipStream_t stream) {
  const int T = 2048;
  const float* enc = (const float*)d_in[0];
  const float* outv = (const float*)d_in[1];
  auto F = [&](int i) { return (const float*)d_in[i]; };

  size_t off = 0;
  auto alloc = [&](size_t bytes) {
    void* p = (char*)d_ws + off;
    off += (bytes + 255) & ~(size_t)255;
    return p;
  };

  // transposed bf16 weights: q,k,v,o,W1,W2 per tag (q,k,v contiguous -> fused QKV BT)
  const int tdK[12] = {1024, 1024, 1024, 1024, 1024, 2048, 1024, 1024, 1024, 1024, 1024, 2048};
  const int tdM[12] = {1024, 1024, 1024, 1024, 2048, 1024, 1024, 1024, 1024, 1024, 2048, 1024};
  const int tdIdx[12] = {2, 4, 6, 8, 10, 12, 18, 20, 22, 24, 26, 28};
  u16* WT_[12];
  for (int i = 0; i < 12; ++i) WT_[i] = (u16*)alloc((size_t)tdK[i] * tdM[i] * 2);

  u16* Xb0 = (u16*)alloc(4096ull * 1024 * 2);
  u16* Eb = (u16*)alloc(4096ull * 1024 * 2);
  u16* Qb = (u16*)alloc(4096ull * 1024 * 2);
  u16* Kb = (u16*)alloc(4096ull * 1024 * 2);
  u16* Vt = (u16*)alloc(4096ull * 1024 * 2);
  u16* Ab = (u16*)alloc(4096ull * 1024 * 2);
  u16* Hb = (u16*)alloc(4096ull * 2048 * 2);   // FFN hidden; doubles as split-K partial 1
  u16* Xbc = (u16*)alloc(4096ull * 1024 * 2);
  float* Rf = (float*)alloc(4096ull * 1024 * 4);  // GEMM f32 out; doubles as split-K partial 0
  float* Xfa = (float*)alloc(4096ull * 1024 * 4);
  float* Xfb = (float*)alloc(4096ull * 1024 * 4);
  float* Lsum = (float*)alloc(2ull * 65536 * 4);  // [2][2*16*2048] lsum partials

  k_cvt2<<<8192, 256, 0, stream>>>(outv, enc, Xb0, Eb, 4096 * 1024 / 4);

  WTJobs jobs;
  int start = 0;
  for (int i = 0; i < 12; ++i) {
    int msh = (tdM[i] == 2048) ? 6 : 5;
    jobs.j[i] = {F(tdIdx[i]), WT_[i], tdK[i], tdM[i], msh, start};
    start += (tdM[i] >> 5) * (tdK[i] >> 5);
  }
  k_wT_all<<<start, dim3(32, 8), 0, stream>>>(jobs);

  float* OP0 = Rf;
  float* OP1 = (float*)Hb;
  float* L0 = Lsum;
  float* L1 = Lsum + 65536;

  dim3 gq(24, 32);     // fused QKV: N=3072, 128x128 2-wave tiles
  dim3 g1k(16, 32);    // N=1024, 128x64 4-wave (proven)
  dim3 gf1(16, 32);    // FFN1 N=2048, 128x128 2-wave tiles
  dim3 gac(32, 16, 2); // causal: 16 q-tiles (128 rows) x 2 kv-halves
  dim3 gan(16, 16, 2); // noncausal: 16 q-tiles (128 rows)

  // ---- dd block ----
  k_qkv2<<<gq, 128, 0, stream>>>(Xb0, Xb0, WT_[0], F(3), F(5), F(7), Qb, Kb, Vt, 1024);
  k_attn<true><<<gac, 512, 0, stream>>>(Qb, Kb, Vt, Ab, OP0, OP1, L0, L1, T);
  k_amrg<<<4096, 256, 0, stream>>>(OP0, OP1, L0, L1, Ab);
  k_gemm<2, 0><<<g1k, 256, 0, stream>>>(Ab, 1024, WT_[3], F(9), Rf, 1024, 1024);
  k_ln<<<4096, 256, 0, stream>>>(Rf, outv, F(14), F(15), Xfa, Xbc);
  k_gemm2<2><<<gf1, 128, 0, stream>>>(Xbc, 1024, WT_[4], F(11), Hb, 2048, 1024);
  k_gemm<2, 0><<<g1k, 256, 0, stream>>>(Hb, 2048, WT_[5], F(13), Rf, 1024, 2048);
  k_ln<<<4096, 256, 0, stream>>>(Rf, Xfa, F(16), F(17), Xfb, Xbc);

  // ---- ed block ----
  k_qkv2<<<gq, 128, 0, stream>>>(Xbc, Eb, WT_[6], F(19), F(21), F(23), Qb, Kb, Vt, 1024);
  k_attn<false><<<gan, 512, 0, stream>>>(Qb, Kb, Vt, Ab, OP0, OP1, L0, L1, T);
  k_gemm<2, 0><<<g1k, 256, 0, stream>>>(Ab, 1024, WT_[9], F(25), Rf, 1024, 1024);
  k_ln<<<4096, 256, 0, stream>>>(Rf, Xfb, F(30), F(31), Xfa, Xbc);
  k_gemm2<2><<<gf1, 128, 0, stream>>>(Xbc, 1024, WT_[10], F(27), Hb, 2048, 1024);
  k_gemm<2, 0><<<g1k, 256, 0, stream>>>(Hb, 2048, WT_[11], F(29), Rf, 1024, 2048);
  k_ln<<<4096, 256, 0, stream>>>(Rf, Xfa, F(32), F(33), (float*)d_out, (u16*)nullptr);
}

// Round 12
// 444.583 us; speedup vs baseline: 1.0998x; 1.0998x over previous
//
#include <hip/hip_runtime.h>
#include <stdint.h>

#define DEV __device__ __forceinline__
typedef unsigned short u16;
typedef __attribute__((ext_vector_type(8))) short bf16x8;
typedef __attribute__((ext_vector_type(4))) float f32x4;

#define AS1 __attribute__((address_space(1)))
#define AS3 __attribute__((address_space(3)))
#define WAITVM0 asm volatile("s_waitcnt vmcnt(0)" ::: "memory")
// scores pre-scaled by 1/sqrt(64) * log2(e) inside the Q-projection epilogue
#define QSCALE 0.18033688011112042f

DEV u16 f2bf(float f) {
  union { float f; uint32_t u; } x; x.f = f;
  uint32_t r = x.u + 0x7fffu + ((x.u >> 16) & 1u);
  return (u16)(r >> 16);
}

DEV uint32_t cvt_pk_bf16(float a, float b) {
  uint32_t r;
  asm("v_cvt_pk_bf16_f32 %0, %1, %2" : "=v"(r) : "v"(a), "v"(b));
  return r;
}

// ---------------- f32 -> bf16 convert, two tensors in one launch ----------------
__global__ __launch_bounds__(256) void k_cvt2(const float* __restrict__ a, const float* __restrict__ bsrc,
                                              u16* __restrict__ oa, u16* __restrict__ ob, int n4) {
  int i = blockIdx.x * blockDim.x + threadIdx.x;
  const float* s;
  u16* o;
  int k;
  if (i < n4) { s = a; o = oa; k = i; }
  else        { s = bsrc; o = ob; k = i - n4; }
  float4 v = reinterpret_cast<const float4*>(s)[k];
  reinterpret_cast<ushort4*>(o)[k] = make_ushort4(f2bf(v.x), f2bf(v.y), f2bf(v.z), f2bf(v.w));
}

// ---------------- batched weight transpose+convert: W f32 [K][M] -> WT bf16 [M][K] ----------------
struct WTJob { const float* W; u16* WT; int K, M, msh, start; };
struct WTJobs { WTJob j[12]; };

__global__ void k_wT_all(WTJobs jobs) {
  __shared__ float tile[32][33];
  int b = blockIdx.x;
  int i = 0;
#pragma unroll
  for (int t = 1; t < 12; ++t)
    if (b >= jobs.j[t].start) i = t;
  const WTJob J = jobs.j[i];
  int rel = b - J.start;
  int m0 = (rel & ((1 << J.msh) - 1)) << 5;
  int k0 = (rel >> J.msh) << 5;
  int tx = threadIdx.x, ty = threadIdx.y;  // (32,8)
#pragma unroll
  for (int q = 0; q < 4; ++q)
    tile[ty + q * 8][tx] = J.W[(size_t)(k0 + ty + q * 8) * J.M + m0 + tx];
  __syncthreads();
#pragma unroll
  for (int q = 0; q < 4; ++q)
    J.WT[(size_t)(m0 + ty + q * 8) * J.K + k0 + tx] = f2bf(tile[tx][ty + q * 8]);
}

// ---- global->LDS staging of an R x 64 bf16 tile (128B rows), 256 threads ----
template<int R>
DEV void stage_tile(const u16* __restrict__ g, int strideElems, u16* lds, int tid, int wv) {
#pragma unroll
  for (int t = 0; t < R / 32; ++t) {
    int idx = t * 256 + tid;
    int row = idx >> 3;
    int b = (idx & 7) << 4;
    int sb = b ^ ((row & 7) << 4);
    const char* src = (const char*)g + (size_t)row * strideElems * 2 + sb;
    char* dst = (char*)lds + (size_t)(t * 256 + wv * 64) * 16;  // wave-uniform; HW adds lane*16
    __builtin_amdgcn_global_load_lds((const AS1 void*)src, (AS3 void*)dst, 16, 0, 0);
  }
}

// swizzled b128 fragment read from a 64-col bf16 tile
DEV bf16x8 lds_frag(const u16* lds, int row, int kel) {
  int off = row * 128 + ((kel * 2) ^ ((row & 7) << 4));
  return *(const bf16x8*)((const char*)lds + off);
}

// ---------------- GEMM: C[n][m] = A[n][:] . WT[m][:] + bias[m] ----------------
// 128xBN (BN=JT*32), BK=64, 4 waves, 2-stage dbuf, XCD-aware bijective swizzle.
// (Proven R8 config.) MODE: 0=f32 out, 2=bf16 relu out
template<int JT, int MODE>
__global__ __launch_bounds__(256) void k_gemm(const u16* __restrict__ A, int lda,
                                              const u16* __restrict__ BT,
                                              const float* __restrict__ bias,
                                              void* __restrict__ C, int ldc, int K) {
  constexpr int BN = JT * 32;
  __shared__ __align__(16) u16 A_lds[2][128 * 64];
  __shared__ __align__(16) u16 B_lds[2][BN * 64];
  const int tid = threadIdx.x, lane = tid & 63, wv = tid >> 6;
  const int wm = wv >> 1, wn = wv & 1;
  const int nwg = gridDim.x * gridDim.y;
  const int flat = blockIdx.y * gridDim.x + blockIdx.x;
  const int sw = (flat & 7) * (nwg >> 3) + (flat >> 3);
  const int bx = sw % gridDim.x, by = sw / gridDim.x;
  const int bm0 = by * 128, bn0 = bx * BN;
  const int lr = lane & 15, lk = (lane >> 4) * 8, r0 = (lane >> 4) * 4;

  f32x4 acc[4][JT];
#pragma unroll
  for (int i = 0; i < 4; ++i)
#pragma unroll
    for (int j = 0; j < JT; ++j) acc[i][j] = f32x4{0.f, 0.f, 0.f, 0.f};

  stage_tile<128>(A + (size_t)bm0 * lda, lda, A_lds[0], tid, wv);
  stage_tile<BN>(BT + (size_t)bn0 * K, K, B_lds[0], tid, wv);
  WAITVM0;
  __builtin_amdgcn_s_barrier();

  int cur = 0;
  for (int k0 = 0; k0 < K; k0 += 64) {
    if (k0 + 64 < K) {
      stage_tile<128>(A + (size_t)bm0 * lda + k0 + 64, lda, A_lds[cur ^ 1], tid, wv);
      stage_tile<BN>(BT + (size_t)bn0 * K + k0 + 64, K, B_lds[cur ^ 1], tid, wv);
    }
#pragma unroll
    for (int kk = 0; kk < 2; ++kk) {
      bf16x8 af[4], bfr[JT];
#pragma unroll
      for (int i = 0; i < 4; ++i) af[i] = lds_frag(A_lds[cur], wm * 64 + i * 16 + lr, kk * 32 + lk);
#pragma unroll
      for (int j = 0; j < JT; ++j) bfr[j] = lds_frag(B_lds[cur], wn * (JT * 16) + j * 16 + lr, kk * 32 + lk);
#pragma unroll
      for (int i = 0; i < 4; ++i)
#pragma unroll
        for (int j = 0; j < JT; ++j)
          acc[i][j] = __builtin_amdgcn_mfma_f32_16x16x32_bf16(af[i], bfr[j], acc[i][j], 0, 0, 0);
    }
    WAITVM0;
    __builtin_amdgcn_s_barrier();
    cur ^= 1;
  }

#pragma unroll
  for (int j = 0; j < JT; ++j) {
    int col = bn0 + wn * (JT * 16) + j * 16 + lr;
    float bv = bias[col];
#pragma unroll
    for (int i = 0; i < 4; ++i) {
      int rowb = bm0 + wm * 64 + i * 16 + r0;
      if constexpr (MODE == 0) {
#pragma unroll
        for (int r = 0; r < 4; ++r)
          ((float*)C)[(size_t)(rowb + r) * ldc + col] = acc[i][j][r] + bv;
      } else {
#pragma unroll
        for (int r = 0; r < 4; ++r) {
          float v = fmaxf(acc[i][j][r] + bv, 0.f);
          ((u16*)C)[(size_t)(rowb + r) * ldc + col] = f2bf(v);
        }
      }
    }
  }
}

// ---------------- fused QKV projection: 128x128 tile (4 waves, 64x64/wave), N=3072 ----------------
// A/B: JT=2 -> JT=4 equivalent. Grid (24,32)=768 blocks, 64KB LDS -> 2 blocks/CU, 8 waves/CU.
__global__ __launch_bounds__(256) void k_qkv(const u16* __restrict__ Aq, const u16* __restrict__ Akv,
                                             const u16* __restrict__ BT,
                                             const float* __restrict__ bq, const float* __restrict__ bk,
                                             const float* __restrict__ bv,
                                             u16* __restrict__ Qb, u16* __restrict__ Kb,
                                             u16* __restrict__ Vt, int K) {
  __shared__ __align__(16) u16 A_lds[2][128 * 64];
  __shared__ __align__(16) u16 B_lds[2][128 * 64];
  const int tid = threadIdx.x, lane = tid & 63, wv = tid >> 6;
  const int wm = wv >> 1, wn = wv & 1;
  const int nwg = gridDim.x * gridDim.y;
  const int flat = blockIdx.y * gridDim.x + blockIdx.x;
  const int sw = (flat & 7) * (nwg >> 3) + (flat >> 3);
  const int bx = sw % gridDim.x, by = sw / gridDim.x;
  const int bm0 = by * 128, bn0 = bx * 128;
  const int seg = bn0 >> 10;
  const u16* A = (seg == 0) ? Aq : Akv;
  const int lr = lane & 15, lk = (lane >> 4) * 8, r0 = (lane >> 4) * 4;

  f32x4 acc[4][4];
#pragma unroll
  for (int i = 0; i < 4; ++i)
#pragma unroll
    for (int j = 0; j < 4; ++j) acc[i][j] = f32x4{0.f, 0.f, 0.f, 0.f};

  stage_tile<128>(A + (size_t)bm0 * K, K, A_lds[0], tid, wv);
  stage_tile<128>(BT + (size_t)bn0 * K, K, B_lds[0], tid, wv);
  WAITVM0;
  __builtin_amdgcn_s_barrier();

  int cur = 0;
  for (int k0 = 0; k0 < K; k0 += 64) {
    if (k0 + 64 < K) {
      stage_tile<128>(A + (size_t)bm0 * K + k0 + 64, K, A_lds[cur ^ 1], tid, wv);
      stage_tile<128>(BT + (size_t)bn0 * K + k0 + 64, K, B_lds[cur ^ 1], tid, wv);
    }
#pragma unroll
    for (int kk = 0; kk < 2; ++kk) {
      bf16x8 af[4], bfr[4];
#pragma unroll
      for (int i = 0; i < 4; ++i) af[i] = lds_frag(A_lds[cur], wm * 64 + i * 16 + lr, kk * 32 + lk);
#pragma unroll
      for (int j = 0; j < 4; ++j) bfr[j] = lds_frag(B_lds[cur], wn * 64 + j * 16 + lr, kk * 32 + lk);
#pragma unroll
      for (int i = 0; i < 4; ++i)
#pragma unroll
        for (int j = 0; j < 4; ++j)
          acc[i][j] = __builtin_amdgcn_mfma_f32_16x16x32_bf16(af[i], bfr[j], acc[i][j], 0, 0, 0);
    }
    WAITVM0;
    __builtin_amdgcn_s_barrier();
    cur ^= 1;
  }

#pragma unroll
  for (int j = 0; j < 4; ++j) {
    int col = bn0 + wn * 64 + j * 16 + lr;
    int cl = col & 1023;
#pragma unroll
    for (int i = 0; i < 4; ++i) {
      int rowb = bm0 + wm * 64 + i * 16 + r0;
      if (seg == 0) {
        float bb = bq[cl];
#pragma unroll
        for (int r = 0; r < 4; ++r)
          Qb[(size_t)(rowb + r) * 1024 + cl] = f2bf((acc[i][j][r] + bb) * QSCALE);
      } else if (seg == 1) {
        float bb = bk[cl];
#pragma unroll
        for (int r = 0; r < 4; ++r)
          Kb[(size_t)(rowb + r) * 1024 + cl] = f2bf(acc[i][j][r] + bb);
      } else {
        float bb = bv[cl];
        int bidx = rowb >> 11, t = rowb & 2047;
        ushort4 o = make_ushort4(f2bf(acc[i][j][0] + bb), f2bf(acc[i][j][1] + bb),
                                 f2bf(acc[i][j][2] + bb), f2bf(acc[i][j][3] + bb));
        *reinterpret_cast<ushort4*>(&Vt[((size_t)bidx * 1024 + cl) * 2048 + t]) = o;
      }
    }
  }
}

// ---------------- fused residual LayerNorm (row=1024), dual f32/bf16 out ----------------
__global__ __launch_bounds__(256) void k_ln(const float* __restrict__ Rm, const float* __restrict__ X,
                                            const float* __restrict__ g, const float* __restrict__ be,
                                            float* __restrict__ Y, u16* __restrict__ Yb) {
  int row = blockIdx.x;
  size_t base4 = (size_t)row * 256;
  int t = threadIdx.x;
  float4 a = reinterpret_cast<const float4*>(Rm)[base4 + t];
  float4 x = reinterpret_cast<const float4*>(X)[base4 + t];
  float v0 = a.x + x.x, v1 = a.y + x.y, v2 = a.z + x.z, v3 = a.w + x.w;
  float s = v0 + v1 + v2 + v3;
  float ss = v0 * v0 + v1 * v1 + v2 * v2 + v3 * v3;
#pragma unroll
  for (int m = 1; m < 64; m <<= 1) { s += __shfl_xor(s, m); ss += __shfl_xor(ss, m); }
  __shared__ float red[8];
  int wv = t >> 6;
  if ((t & 63) == 0) { red[wv] = s; red[4 + wv] = ss; }
  __syncthreads();
  s = red[0] + red[1] + red[2] + red[3];
  ss = red[4] + red[5] + red[6] + red[7];
  float mean = s * (1.f / 1024.f);
  float var = ss * (1.f / 1024.f) - mean * mean;
  float rstd = rsqrtf(var + 1e-5f);
  float4 gv = reinterpret_cast<const float4*>(g)[t];
  float4 bv = reinterpret_cast<const float4*>(be)[t];
  float o0 = (v0 - mean) * rstd * gv.x + bv.x;
  float o1 = (v1 - mean) * rstd * gv.y + bv.y;
  float o2 = (v2 - mean) * rstd * gv.z + bv.z;
  float o3 = (v3 - mean) * rstd * gv.w + bv.w;
  reinterpret_cast<float4*>(Y)[base4 + t] = make_float4(o0, o1, o2, o3);
  if (Yb) {
    ushort4 ob = make_ushort4(f2bf(o0), f2bf(o1), f2bf(o2), f2bf(o3));
    reinterpret_cast<ushort4*>(Yb)[base4 + t] = ob;
  }
}

// ---------------- flash attention: 8 waves, QBLK=128, 3-buffer ring, counted vmcnt ----------------
// (round-8 proven config: 70us.) Causal: KV-split-2 with f32 partials.
template<bool CAUSAL>
__global__ __launch_bounds__(512) void k_attn(const u16* __restrict__ Q, const u16* __restrict__ Kg,
                                              const u16* __restrict__ Vt, u16* __restrict__ O,
                                              float* __restrict__ OP0, float* __restrict__ OP1,
                                              float* __restrict__ L0, float* __restrict__ L1, int T) {
  __shared__ __align__(16) u16 K_lds[3][64 * 64];
  __shared__ __align__(16) u16 V_lds[3][64 * 64];   // V^T tiles: [dh][kv]
  __shared__ __align__(16) u16 p_lds[8][16 * 64];   // per-wave P rows, swizzled
  const int tid = threadIdx.x, lane = tid & 63, wv = tid >> 6;
  const int h = blockIdx.y, b = blockIdx.z;
  const int lq = lane & 15, g = lane >> 4;
  const int swz = (lq & 7) << 4;
  const int fb0 = lq * 128 + ((g * 16) ^ swz);
  const int fb1 = lq * 128 + ((g * 16 + 64) ^ swz);
  const size_t qkbase = ((size_t)b * T) * 1024 + h * 64;
  const size_t vbase = ((size_t)b * 1024 + h * 64) * T;

  int qx, st, en;
  if constexpr (CAUSAL) {
    qx = 15 - (blockIdx.x >> 1);               // heavy q-tiles dispatch first
    const int s = blockIdx.x & 1;
    const int ntf = 2 * qx + 2, half = qx + 1;
    st = s ? half : 0;
    en = s ? ntf : half;
  } else {
    qx = blockIdx.x;
    st = 0;
    en = T >> 6;
  }
  const int qw = qx * 128 + wv * 16;
  const int dtile = qw >> 6;                    // this wave's diagonal kv-tile

  bf16x8 aq0, aq1;
  {
    const u16* qp_ = Q + qkbase + (size_t)(qw + lq) * 1024 + g * 8;
    aq0 = *reinterpret_cast<const bf16x8*>(qp_);
    aq1 = *reinterpret_cast<const bf16x8*>(qp_ + 32);
  }

  // staging: 512 threads, 1 K-load + 1 V-load each (16B), pre-swizzled source
  const int srow = tid >> 3;
  const int ssb = ((tid & 7) << 4) ^ ((srow & 7) << 4);
  const char* ksrc = (const char*)(Kg + qkbase) + (size_t)srow * 2048 + ssb + (size_t)st * 131072;
  const char* vsrc = (const char*)(Vt + vbase) + (size_t)srow * ((size_t)T * 2) + ssb + (size_t)st * 128;
  const uint32_t doff = (uint32_t)(wv << 10);   // wave-uniform LDS base; HW adds lane*16

  auto stage = [&](int buf) {
    __builtin_amdgcn_global_load_lds((const AS1 void*)ksrc, (AS3 void*)((char*)K_lds[buf] + doff), 16, 0, 0);
    __builtin_amdgcn_global_load_lds((const AS1 void*)vsrc, (AS3 void*)((char*)V_lds[buf] + doff), 16, 0, 0);
    ksrc += 131072;   // 64 rows * 2048B
    vsrc += 128;      // 64 kv cols * 2B
  };

  f32x4 acc[4];
  float lsum = 0.f;
#pragma unroll
  for (int j = 0; j < 4; ++j) acc[j] = f32x4{0.f, 0.f, 0.f, 0.f};

  char* pw = (char*)p_lds[wv];

  auto qstep = [&](bool domask, int kv0, const char* kb, const char* vb) {
    f32x4 st_[4];
    __builtin_amdgcn_s_setprio(1);
#pragma unroll
    for (int j = 0; j < 4; ++j) {
      bf16x8 bk0 = *reinterpret_cast<const bf16x8*>(kb + fb0 + j * 2048);
      bf16x8 bk1 = *reinterpret_cast<const bf16x8*>(kb + fb1 + j * 2048);
      f32x4 t0 = f32x4{0.f, 0.f, 0.f, 0.f};
      t0 = __builtin_amdgcn_mfma_f32_16x16x32_bf16(bk0, aq0, t0, 0, 0, 0);
      t0 = __builtin_amdgcn_mfma_f32_16x16x32_bf16(bk1, aq1, t0, 0, 0, 0);
      st_[j] = t0;
    }
    __builtin_amdgcn_s_setprio(0);
    uint32_t pk[8];
    if (domask) {
      const int qrow = qw + lq;
#pragma unroll
      for (int j = 0; j < 4; ++j) {
        float p0 = __builtin_exp2f(st_[j][0]);
        float p1 = __builtin_exp2f(st_[j][1]);
        float p2 = __builtin_exp2f(st_[j][2]);
        float p3 = __builtin_exp2f(st_[j][3]);
        int kvb = kv0 + j * 16 + g * 4;
        p0 = (kvb > qrow) ? 0.f : p0;
        p1 = (kvb + 1 > qrow) ? 0.f : p1;
        p2 = (kvb + 2 > qrow) ? 0.f : p2;
        p3 = (kvb + 3 > qrow) ? 0.f : p3;
        lsum += (p0 + p1) + (p2 + p3);
        pk[2 * j] = cvt_pk_bf16(p0, p1);
        pk[2 * j + 1] = cvt_pk_bf16(p2, p3);
      }
    } else {
#pragma unroll
      for (int j = 0; j < 4; ++j) {
        float p0 = __builtin_exp2f(st_[j][0]);
        float p1 = __builtin_exp2f(st_[j][1]);
        float p2 = __builtin_exp2f(st_[j][2]);
        float p3 = __builtin_exp2f(st_[j][3]);
        lsum += (p0 + p1) + (p2 + p3);
        pk[2 * j] = cvt_pk_bf16(p0, p1);
        pk[2 * j + 1] = cvt_pk_bf16(p2, p3);
      }
    }
#pragma unroll
    for (int j = 0; j < 4; ++j)
      *reinterpret_cast<uint2*>(pw + lq * 128 + ((j * 32 + g * 8) ^ swz)) =
          make_uint2(pk[2 * j], pk[2 * j + 1]);
    bf16x8 pf0 = *reinterpret_cast<const bf16x8*>(pw + fb0);
    bf16x8 pf1 = *reinterpret_cast<const bf16x8*>(pw + fb1);
    __builtin_amdgcn_s_setprio(1);
#pragma unroll
    for (int j2 = 0; j2 < 4; ++j2) {
      bf16x8 v0 = *reinterpret_cast<const bf16x8*>(vb + fb0 + j2 * 2048);
      bf16x8 v1 = *reinterpret_cast<const bf16x8*>(vb + fb1 + j2 * 2048);
      acc[j2] = __builtin_amdgcn_mfma_f32_16x16x32_bf16(v0, pf0, acc[j2], 0, 0, 0);
      acc[j2] = __builtin_amdgcn_mfma_f32_16x16x32_bf16(v1, pf1, acc[j2], 0, 0, 0);
    }
    __builtin_amdgcn_s_setprio(0);
  };

  // prologue: fill ring with tiles st, st+1
  stage(0);
  if (st + 1 < en) {
    stage(1);
    asm volatile("s_waitcnt vmcnt(2)" ::: "memory");   // tile st done; st+1 in flight
  } else {
    WAITVM0;
  }
  __builtin_amdgcn_s_barrier();

  for (int it = st; it < en; ++it) {
    const int idx = it - st;
    if (it + 2 < en) stage((idx + 2) % 3);
    const char* kb = (const char*)K_lds[idx % 3];
    const char* vb = (const char*)V_lds[idx % 3];
    if (!CAUSAL || it <= dtile)                        // wave-uniform skip of masked tiles
      qstep(CAUSAL && it == dtile, it << 6, kb, vb);
    if (it + 2 < en) {
      asm volatile("s_waitcnt vmcnt(2)" ::: "memory"); // tile it+1 done; it+2 in flight
    } else {
      WAITVM0;
    }
    __builtin_amdgcn_s_barrier();
  }

  lsum += __shfl_xor(lsum, 16);
  lsum += __shfl_xor(lsum, 32);
  if constexpr (CAUSAL) {
    float* OP = (blockIdx.x & 1) ? OP1 : OP0;
    float* Lp = (blockIdx.x & 1) ? L1 : L0;
    const int row = (b * 16 + h) * 2048 + qw + lq;
    float* pr = OP + (size_t)row * 64;
#pragma unroll
    for (int j2 = 0; j2 < 4; ++j2)
      *reinterpret_cast<f32x4*>(pr + j2 * 16 + g * 4) = acc[j2];
    if (g == 0) Lp[row] = lsum;
  } else {
    float inv = 1.f / lsum;
    size_t rb = qkbase + (size_t)(qw + lq) * 1024;
#pragma unroll
    for (int j2 = 0; j2 < 4; ++j2) {
      ushort4 o = make_ushort4(f2bf(acc[j2][0] * inv), f2bf(acc[j2][1] * inv),
                               f2bf(acc[j2][2] * inv), f2bf(acc[j2][3] * inv));
      *reinterpret_cast<ushort4*>(&O[rb + j2 * 16 + g * 4]) = o;
    }
  }
}

// ---------------- split-K attention merge: O = (O0+O1)/(l0+l1), f32 -> bf16 [b][q][h*64+dh] ----------------
__global__ __launch_bounds__(256) void k_amrg(const float* __restrict__ P0, const float* __restrict__ P1,
                                              const float* __restrict__ L0, const float* __restrict__ L1,
                                              u16* __restrict__ Ab) {
  int i = blockIdx.x * 256 + threadIdx.x;   // 1M threads: [2][16][2048] rows x 16 f32x4
  int row = i >> 4, d4 = (i & 15) << 2;
  f32x4 a = *reinterpret_cast<const f32x4*>(&P0[(size_t)row * 64 + d4]);
  f32x4 c = *reinterpret_cast<const f32x4*>(&P1[(size_t)row * 64 + d4]);
  float inv = 1.f / (L0[row] + L1[row]);
  int bh = row >> 11, q = row & 2047, bb = bh >> 4, hh = bh & 15;
  size_t dst = ((size_t)(bb * 2048 + q)) * 1024 + hh * 64 + d4;
  ushort4 o = make_ushort4(f2bf((a[0] + c[0]) * inv), f2bf((a[1] + c[1]) * inv),
                           f2bf((a[2] + c[2]) * inv), f2bf((a[3] + c[3]) * inv));
  *reinterpret_cast<ushort4*>(&Ab[dst]) = o;
}

// ---------------- host orchestration ----------------
extern "C" void kernel_launch(void* const* d_in, const int* in_sizes, int n_in,
                              void* d_out, int out_size, void* d_ws, size_t ws_size,
                              hipStream_t stream) {
  const int T = 2048;
  const float* enc = (const float*)d_in[0];
  const float* outv = (const float*)d_in[1];
  auto F = [&](int i) { return (const float*)d_in[i]; };

  size_t off = 0;
  auto alloc = [&](size_t bytes) {
    void* p = (char*)d_ws + off;
    off += (bytes + 255) & ~(size_t)255;
    return p;
  };

  // transposed bf16 weights: q,k,v,o,W1,W2 per tag (q,k,v contiguous -> fused QKV BT)
  const int tdK[12] = {1024, 1024, 1024, 1024, 1024, 2048, 1024, 1024, 1024, 1024, 1024, 2048};
  const int tdM[12] = {1024, 1024, 1024, 1024, 2048, 1024, 1024, 1024, 1024, 1024, 2048, 1024};
  const int tdIdx[12] = {2, 4, 6, 8, 10, 12, 18, 20, 22, 24, 26, 28};
  u16* WT_[12];
  for (int i = 0; i < 12; ++i) WT_[i] = (u16*)alloc((size_t)tdK[i] * tdM[i] * 2);

  u16* Xb0 = (u16*)alloc(4096ull * 1024 * 2);
  u16* Eb = (u16*)alloc(4096ull * 1024 * 2);
  u16* Qb = (u16*)alloc(4096ull * 1024 * 2);
  u16* Kb = (u16*)alloc(4096ull * 1024 * 2);
  u16* Vt = (u16*)alloc(4096ull * 1024 * 2);
  u16* Ab = (u16*)alloc(4096ull * 1024 * 2);
  u16* Hb = (u16*)alloc(4096ull * 2048 * 2);   // FFN hidden; doubles as split-K partial 1
  u16* Xbc = (u16*)alloc(4096ull * 1024 * 2);
  float* Rf = (float*)alloc(4096ull * 1024 * 4);  // GEMM f32 out; doubles as split-K partial 0
  float* Xfa = (float*)alloc(4096ull * 1024 * 4);
  float* Xfb = (float*)alloc(4096ull * 1024 * 4);
  float* Lsum = (float*)alloc(2ull * 65536 * 4);  // [2][2*16*2048] lsum partials

  k_cvt2<<<8192, 256, 0, stream>>>(outv, enc, Xb0, Eb, 4096 * 1024 / 4);

  WTJobs jobs;
  int start = 0;
  for (int i = 0; i < 12; ++i) {
    int msh = (tdM[i] == 2048) ? 6 : 5;
    jobs.j[i] = {F(tdIdx[i]), WT_[i], tdK[i], tdM[i], msh, start};
    start += (tdM[i] >> 5) * (tdK[i] >> 5);
  }
  k_wT_all<<<start, dim3(32, 8), 0, stream>>>(jobs);

  float* OP0 = Rf;
  float* OP1 = (float*)Hb;
  float* L0 = Lsum;
  float* L1 = Lsum + 65536;

  dim3 gq(24, 32);     // fused QKV: N=3072, 128x128 4-wave tiles (A/B vs 128x64)
  dim3 g1k(16, 32);    // N=1024, JT=2 (proven)
  dim3 g2k(16, 32);    // FFN1 N=2048, JT=4 (proven since R3)
  dim3 gac(32, 16, 2); // causal: 16 q-tiles (128 rows) x 2 kv-halves
  dim3 gan(16, 16, 2); // noncausal: 16 q-tiles (128 rows)

  // ---- dd block ----
  k_qkv<<<gq, 256, 0, stream>>>(Xb0, Xb0, WT_[0], F(3), F(5), F(7), Qb, Kb, Vt, 1024);
  k_attn<true><<<gac, 512, 0, stream>>>(Qb, Kb, Vt, Ab, OP0, OP1, L0, L1, T);
  k_amrg<<<4096, 256, 0, stream>>>(OP0, OP1, L0, L1, Ab);
  k_gemm<2, 0><<<g1k, 256, 0, stream>>>(Ab, 1024, WT_[3], F(9), Rf, 1024, 1024);
  k_ln<<<4096, 256, 0, stream>>>(Rf, outv, F(14), F(15), Xfa, Xbc);
  k_gemm<4, 2><<<g2k, 256, 0, stream>>>(Xbc, 1024, WT_[4], F(11), Hb, 2048, 1024);
  k_gemm<2, 0><<<g1k, 256, 0, stream>>>(Hb, 2048, WT_[5], F(13), Rf, 1024, 2048);
  k_ln<<<4096, 256, 0, stream>>>(Rf, Xfa, F(16), F(17), Xfb, Xbc);

  // ---- ed block ----
  k_qkv<<<gq, 256, 0, stream>>>(Xbc, Eb, WT_[6], F(19), F(21), F(23), Qb, Kb, Vt, 1024);
  k_attn<false><<<gan, 512, 0, stream>>>(Qb, Kb, Vt, Ab, OP0, OP1, L0, L1, T);
  k_gemm<2, 0><<<g1k, 256, 0, stream>>>(Ab, 1024, WT_[9], F(25), Rf, 1024, 1024);
  k_ln<<<4096, 256, 0, stream>>>(Rf, Xfb, F(30), F(31), Xfa, Xbc);
  k_gemm<4, 2><<<g2k, 256, 0, stream>>>(Xbc, 1024, WT_[10], F(27), Hb, 2048, 1024);
  k_gemm<2, 0><<<g1k, 256, 0, stream>>>(Hb, 2048, WT_[11], F(29), Rf, 1024, 2048);
  k_ln<<<4096, 256, 0, stream>>>(Rf, Xfa, F(32), F(33), (float*)d_out, (u16*)nullptr);
}

// Round 13
// 423.294 us; speedup vs baseline: 1.1551x; 1.0503x over previous
//
#include <hip/hip_runtime.h>
#include <stdint.h>

#define DEV __device__ __forceinline__
typedef unsigned short u16;
typedef __attribute__((ext_vector_type(8))) short bf16x8;
typedef __attribute__((ext_vector_type(4))) float f32x4;

#define AS1 __attribute__((address_space(1)))
#define AS3 __attribute__((address_space(3)))
#define WAITVM0 asm volatile("s_waitcnt vmcnt(0)" ::: "memory")
// scores pre-scaled by 1/sqrt(64) * log2(e) inside the Q-projection epilogue
#define QSCALE 0.18033688011112042f

DEV u16 f2bf(float f) {
  union { float f; uint32_t u; } x; x.f = f;
  uint32_t r = x.u + 0x7fffu + ((x.u >> 16) & 1u);
  return (u16)(r >> 16);
}

DEV float bf2f(u16 h) {
  union { uint32_t u; float f; } x; x.u = ((uint32_t)h) << 16;
  return x.f;
}

DEV uint32_t cvt_pk_bf16(float a, float b) {
  uint32_t r;
  asm("v_cvt_pk_bf16_f32 %0, %1, %2" : "=v"(r) : "v"(a), "v"(b));
  return r;
}

// ---------------- f32 -> bf16 convert, two tensors in one launch ----------------
__global__ __launch_bounds__(256) void k_cvt2(const float* __restrict__ a, const float* __restrict__ bsrc,
                                              u16* __restrict__ oa, u16* __restrict__ ob, int n4) {
  int i = blockIdx.x * blockDim.x + threadIdx.x;
  const float* s;
  u16* o;
  int k;
  if (i < n4) { s = a; o = oa; k = i; }
  else        { s = bsrc; o = ob; k = i - n4; }
  float4 v = reinterpret_cast<const float4*>(s)[k];
  reinterpret_cast<ushort4*>(o)[k] = make_ushort4(f2bf(v.x), f2bf(v.y), f2bf(v.z), f2bf(v.w));
}

// ---------------- batched weight transpose+convert: W f32 [K][M] -> WT bf16 [M][K] ----------------
struct WTJob { const float* W; u16* WT; int K, M, msh, start; };
struct WTJobs { WTJob j[12]; };

__global__ void k_wT_all(WTJobs jobs) {
  __shared__ float tile[32][33];
  int b = blockIdx.x;
  int i = 0;
#pragma unroll
  for (int t = 1; t < 12; ++t)
    if (b >= jobs.j[t].start) i = t;
  const WTJob J = jobs.j[i];
  int rel = b - J.start;
  int m0 = (rel & ((1 << J.msh) - 1)) << 5;
  int k0 = (rel >> J.msh) << 5;
  int tx = threadIdx.x, ty = threadIdx.y;  // (32,8)
#pragma unroll
  for (int q = 0; q < 4; ++q)
    tile[ty + q * 8][tx] = J.W[(size_t)(k0 + ty + q * 8) * J.M + m0 + tx];
  __syncthreads();
#pragma unroll
  for (int q = 0; q < 4; ++q)
    J.WT[(size_t)(m0 + ty + q * 8) * J.K + k0 + tx] = f2bf(tile[tx][ty + q * 8]);
}

// ---- global->LDS staging of an R x 64 bf16 tile (128B rows), 256 threads ----
template<int R>
DEV void stage_tile(const u16* __restrict__ g, int strideElems, u16* lds, int tid, int wv) {
#pragma unroll
  for (int t = 0; t < R / 32; ++t) {
    int idx = t * 256 + tid;
    int row = idx >> 3;
    int b = (idx & 7) << 4;
    int sb = b ^ ((row & 7) << 4);
    const char* src = (const char*)g + (size_t)row * strideElems * 2 + sb;
    char* dst = (char*)lds + (size_t)(t * 256 + wv * 64) * 16;  // wave-uniform; HW adds lane*16
    __builtin_amdgcn_global_load_lds((const AS1 void*)src, (AS3 void*)dst, 16, 0, 0);
  }
}

// swizzled b128 fragment read from a 64-col bf16 tile
DEV bf16x8 lds_frag(const u16* lds, int row, int kel) {
  int off = row * 128 + ((kel * 2) ^ ((row & 7) << 4));
  return *(const bf16x8*)((const char*)lds + off);
}

// ---------------- GEMM: C[n][m] = A[n][:] . WT[m][:] + bias[m] ----------------
// 128xBN (BN=JT*32), BK=64, 4 waves, 2-stage dbuf, XCD-aware bijective swizzle.
// MODE: 1=bf16 out, 2=bf16 relu out
template<int JT, int MODE>
__global__ __launch_bounds__(256) void k_gemm(const u16* __restrict__ A, int lda,
                                              const u16* __restrict__ BT,
                                              const float* __restrict__ bias,
                                              u16* __restrict__ C, int ldc, int K) {
  constexpr int BN = JT * 32;
  __shared__ __align__(16) u16 A_lds[2][128 * 64];
  __shared__ __align__(16) u16 B_lds[2][BN * 64];
  const int tid = threadIdx.x, lane = tid & 63, wv = tid >> 6;
  const int wm = wv >> 1, wn = wv & 1;
  const int nwg = gridDim.x * gridDim.y;
  const int flat = blockIdx.y * gridDim.x + blockIdx.x;
  const int sw = (flat & 7) * (nwg >> 3) + (flat >> 3);
  const int bx = sw % gridDim.x, by = sw / gridDim.x;
  const int bm0 = by * 128, bn0 = bx * BN;
  const int lr = lane & 15, lk = (lane >> 4) * 8, r0 = (lane >> 4) * 4;

  f32x4 acc[4][JT];
#pragma unroll
  for (int i = 0; i < 4; ++i)
#pragma unroll
    for (int j = 0; j < JT; ++j) acc[i][j] = f32x4{0.f, 0.f, 0.f, 0.f};

  stage_tile<128>(A + (size_t)bm0 * lda, lda, A_lds[0], tid, wv);
  stage_tile<BN>(BT + (size_t)bn0 * K, K, B_lds[0], tid, wv);
  WAITVM0;
  __builtin_amdgcn_s_barrier();

  int cur = 0;
  for (int k0 = 0; k0 < K; k0 += 64) {
    if (k0 + 64 < K) {
      stage_tile<128>(A + (size_t)bm0 * lda + k0 + 64, lda, A_lds[cur ^ 1], tid, wv);
      stage_tile<BN>(BT + (size_t)bn0 * K + k0 + 64, K, B_lds[cur ^ 1], tid, wv);
    }
#pragma unroll
    for (int kk = 0; kk < 2; ++kk) {
      bf16x8 af[4], bfr[JT];
#pragma unroll
      for (int i = 0; i < 4; ++i) af[i] = lds_frag(A_lds[cur], wm * 64 + i * 16 + lr, kk * 32 + lk);
#pragma unroll
      for (int j = 0; j < JT; ++j) bfr[j] = lds_frag(B_lds[cur], wn * (JT * 16) + j * 16 + lr, kk * 32 + lk);
#pragma unroll
      for (int i = 0; i < 4; ++i)
#pragma unroll
        for (int j = 0; j < JT; ++j)
          acc[i][j] = __builtin_amdgcn_mfma_f32_16x16x32_bf16(af[i], bfr[j], acc[i][j], 0, 0, 0);
    }
    WAITVM0;
    __builtin_amdgcn_s_barrier();
    cur ^= 1;
  }

#pragma unroll
  for (int j = 0; j < JT; ++j) {
    int col = bn0 + wn * (JT * 16) + j * 16 + lr;
    float bv = bias[col];
#pragma unroll
    for (int i = 0; i < 4; ++i) {
      int rowb = bm0 + wm * 64 + i * 16 + r0;
#pragma unroll
      for (int r = 0; r < 4; ++r) {
        float v = acc[i][j][r] + bv;
        if constexpr (MODE == 2) v = fmaxf(v, 0.f);
        C[(size_t)(rowb + r) * ldc + col] = f2bf(v);
      }
    }
  }
}

// ---------------- fused QKV projection: 128x128 tile (4 waves, 64x64/wave), N=3072 ----------------
__global__ __launch_bounds__(256) void k_qkv(const u16* __restrict__ Aq, const u16* __restrict__ Akv,
                                             const u16* __restrict__ BT,
                                             const float* __restrict__ bq, const float* __restrict__ bk,
                                             const float* __restrict__ bv,
                                             u16* __restrict__ Qb, u16* __restrict__ Kb,
                                             u16* __restrict__ Vt, int K) {
  __shared__ __align__(16) u16 A_lds[2][128 * 64];
  __shared__ __align__(16) u16 B_lds[2][128 * 64];
  const int tid = threadIdx.x, lane = tid & 63, wv = tid >> 6;
  const int wm = wv >> 1, wn = wv & 1;
  const int nwg = gridDim.x * gridDim.y;
  const int flat = blockIdx.y * gridDim.x + blockIdx.x;
  const int sw = (flat & 7) * (nwg >> 3) + (flat >> 3);
  const int bx = sw % gridDim.x, by = sw / gridDim.x;
  const int bm0 = by * 128, bn0 = bx * 128;
  const int seg = bn0 >> 10;
  const u16* A = (seg == 0) ? Aq : Akv;
  const int lr = lane & 15, lk = (lane >> 4) * 8, r0 = (lane >> 4) * 4;

  f32x4 acc[4][4];
#pragma unroll
  for (int i = 0; i < 4; ++i)
#pragma unroll
    for (int j = 0; j < 4; ++j) acc[i][j] = f32x4{0.f, 0.f, 0.f, 0.f};

  stage_tile<128>(A + (size_t)bm0 * K, K, A_lds[0], tid, wv);
  stage_tile<128>(BT + (size_t)bn0 * K, K, B_lds[0], tid, wv);
  WAITVM0;
  __builtin_amdgcn_s_barrier();

  int cur = 0;
  for (int k0 = 0; k0 < K; k0 += 64) {
    if (k0 + 64 < K) {
      stage_tile<128>(A + (size_t)bm0 * K + k0 + 64, K, A_lds[cur ^ 1], tid, wv);
      stage_tile<128>(BT + (size_t)bn0 * K + k0 + 64, K, B_lds[cur ^ 1], tid, wv);
    }
#pragma unroll
    for (int kk = 0; kk < 2; ++kk) {
      bf16x8 af[4], bfr[4];
#pragma unroll
      for (int i = 0; i < 4; ++i) af[i] = lds_frag(A_lds[cur], wm * 64 + i * 16 + lr, kk * 32 + lk);
#pragma unroll
      for (int j = 0; j < 4; ++j) bfr[j] = lds_frag(B_lds[cur], wn * 64 + j * 16 + lr, kk * 32 + lk);
#pragma unroll
      for (int i = 0; i < 4; ++i)
#pragma unroll
        for (int j = 0; j < 4; ++j)
          acc[i][j] = __builtin_amdgcn_mfma_f32_16x16x32_bf16(af[i], bfr[j], acc[i][j], 0, 0, 0);
    }
    WAITVM0;
    __builtin_amdgcn_s_barrier();
    cur ^= 1;
  }

#pragma unroll
  for (int j = 0; j < 4; ++j) {
    int col = bn0 + wn * 64 + j * 16 + lr;
    int cl = col & 1023;
#pragma unroll
    for (int i = 0; i < 4; ++i) {
      int rowb = bm0 + wm * 64 + i * 16 + r0;
      if (seg == 0) {
        float bb = bq[cl];
#pragma unroll
        for (int r = 0; r < 4; ++r)
          Qb[(size_t)(rowb + r) * 1024 + cl] = f2bf((acc[i][j][r] + bb) * QSCALE);
      } else if (seg == 1) {
        float bb = bk[cl];
#pragma unroll
        for (int r = 0; r < 4; ++r)
          Kb[(size_t)(rowb + r) * 1024 + cl] = f2bf(acc[i][j][r] + bb);
      } else {
        float bb = bv[cl];
        int bidx = rowb >> 11, t = rowb & 2047;
        ushort4 o = make_ushort4(f2bf(acc[i][j][0] + bb), f2bf(acc[i][j][1] + bb),
                                 f2bf(acc[i][j][2] + bb), f2bf(acc[i][j][3] + bb));
        *reinterpret_cast<ushort4*>(&Vt[((size_t)bidx * 1024 + cl) * 2048 + t]) = o;
      }
    }
  }
}

// ---------------- fused residual LayerNorm, all-bf16 dataflow ----------------
// Rm, X: bf16 rows of 1024. Yb: bf16 out (residual+GEMM input) or null; Yf: f32 out or null.
__global__ __launch_bounds__(256) void k_ln_b(const u16* __restrict__ Rm, const u16* __restrict__ X,
                                              const float* __restrict__ g, const float* __restrict__ be,
                                              u16* __restrict__ Yb, float* __restrict__ Yf) {
  int row = blockIdx.x;
  size_t base4 = (size_t)row * 256;
  int t = threadIdx.x;
  ushort4 a4 = reinterpret_cast<const ushort4*>(Rm)[base4 + t];
  ushort4 x4 = reinterpret_cast<const ushort4*>(X)[base4 + t];
  float v0 = bf2f(a4.x) + bf2f(x4.x), v1 = bf2f(a4.y) + bf2f(x4.y);
  float v2 = bf2f(a4.z) + bf2f(x4.z), v3 = bf2f(a4.w) + bf2f(x4.w);
  float s = v0 + v1 + v2 + v3;
  float ss = v0 * v0 + v1 * v1 + v2 * v2 + v3 * v3;
#pragma unroll
  for (int m = 1; m < 64; m <<= 1) { s += __shfl_xor(s, m); ss += __shfl_xor(ss, m); }
  __shared__ float red[8];
  int wv = t >> 6;
  if ((t & 63) == 0) { red[wv] = s; red[4 + wv] = ss; }
  __syncthreads();
  s = red[0] + red[1] + red[2] + red[3];
  ss = red[4] + red[5] + red[6] + red[7];
  float mean = s * (1.f / 1024.f);
  float var = ss * (1.f / 1024.f) - mean * mean;
  float rstd = rsqrtf(var + 1e-5f);
  float4 gv = reinterpret_cast<const float4*>(g)[t];
  float4 bv = reinterpret_cast<const float4*>(be)[t];
  float o0 = (v0 - mean) * rstd * gv.x + bv.x;
  float o1 = (v1 - mean) * rstd * gv.y + bv.y;
  float o2 = (v2 - mean) * rstd * gv.z + bv.z;
  float o3 = (v3 - mean) * rstd * gv.w + bv.w;
  if (Yb) {
    ushort4 ob = make_ushort4(f2bf(o0), f2bf(o1), f2bf(o2), f2bf(o3));
    reinterpret_cast<ushort4*>(Yb)[base4 + t] = ob;
  }
  if (Yf)
    reinterpret_cast<float4*>(Yf)[base4 + t] = make_float4(o0, o1, o2, o3);
}

// ---------------- flash attention: 8 waves, QBLK=128, 3-buffer ring, counted vmcnt ----------------
// (round-8 proven config.) Causal: KV-split-2 with bf16 partials (fixed-max softmax =>
// partials merge by pure sum; bf16 rounding of unnormalized partials adds <0.5% rel err).
template<bool CAUSAL>
__global__ __launch_bounds__(512) void k_attn(const u16* __restrict__ Q, const u16* __restrict__ Kg,
                                              const u16* __restrict__ Vt, u16* __restrict__ O,
                                              u16* __restrict__ OP0, u16* __restrict__ OP1,
                                              float* __restrict__ L0, float* __restrict__ L1, int T) {
  __shared__ __align__(16) u16 K_lds[3][64 * 64];
  __shared__ __align__(16) u16 V_lds[3][64 * 64];   // V^T tiles: [dh][kv]
  __shared__ __align__(16) u16 p_lds[8][16 * 64];   // per-wave P rows, swizzled
  const int tid = threadIdx.x, lane = tid & 63, wv = tid >> 6;
  const int h = blockIdx.y, b = blockIdx.z;
  const int lq = lane & 15, g = lane >> 4;
  const int swz = (lq & 7) << 4;
  const int fb0 = lq * 128 + ((g * 16) ^ swz);
  const int fb1 = lq * 128 + ((g * 16 + 64) ^ swz);
  const size_t qkbase = ((size_t)b * T) * 1024 + h * 64;
  const size_t vbase = ((size_t)b * 1024 + h * 64) * T;

  int qx, st, en;
  if constexpr (CAUSAL) {
    qx = 15 - (blockIdx.x >> 1);               // heavy q-tiles dispatch first
    const int s = blockIdx.x & 1;
    const int ntf = 2 * qx + 2, half = qx + 1;
    st = s ? half : 0;
    en = s ? ntf : half;
  } else {
    qx = blockIdx.x;
    st = 0;
    en = T >> 6;
  }
  const int qw = qx * 128 + wv * 16;
  const int dtile = qw >> 6;                    // this wave's diagonal kv-tile

  bf16x8 aq0, aq1;
  {
    const u16* qp_ = Q + qkbase + (size_t)(qw + lq) * 1024 + g * 8;
    aq0 = *reinterpret_cast<const bf16x8*>(qp_);
    aq1 = *reinterpret_cast<const bf16x8*>(qp_ + 32);
  }

  // staging: 512 threads, 1 K-load + 1 V-load each (16B), pre-swizzled source
  const int srow = tid >> 3;
  const int ssb = ((tid & 7) << 4) ^ ((srow & 7) << 4);
  const char* ksrc = (const char*)(Kg + qkbase) + (size_t)srow * 2048 + ssb + (size_t)st * 131072;
  const char* vsrc = (const char*)(Vt + vbase) + (size_t)srow * ((size_t)T * 2) + ssb + (size_t)st * 128;
  const uint32_t doff = (uint32_t)(wv << 10);   // wave-uniform LDS base; HW adds lane*16

  auto stage = [&](int buf) {
    __builtin_amdgcn_global_load_lds((const AS1 void*)ksrc, (AS3 void*)((char*)K_lds[buf] + doff), 16, 0, 0);
    __builtin_amdgcn_global_load_lds((const AS1 void*)vsrc, (AS3 void*)((char*)V_lds[buf] + doff), 16, 0, 0);
    ksrc += 131072;   // 64 rows * 2048B
    vsrc += 128;      // 64 kv cols * 2B
  };

  f32x4 acc[4];
  float lsum = 0.f;
#pragma unroll
  for (int j = 0; j < 4; ++j) acc[j] = f32x4{0.f, 0.f, 0.f, 0.f};

  char* pw = (char*)p_lds[wv];

  auto qstep = [&](bool domask, int kv0, const char* kb, const char* vb) {
    f32x4 st_[4];
    __builtin_amdgcn_s_setprio(1);
#pragma unroll
    for (int j = 0; j < 4; ++j) {
      bf16x8 bk0 = *reinterpret_cast<const bf16x8*>(kb + fb0 + j * 2048);
      bf16x8 bk1 = *reinterpret_cast<const bf16x8*>(kb + fb1 + j * 2048);
      f32x4 t0 = f32x4{0.f, 0.f, 0.f, 0.f};
      t0 = __builtin_amdgcn_mfma_f32_16x16x32_bf16(bk0, aq0, t0, 0, 0, 0);
      t0 = __builtin_amdgcn_mfma_f32_16x16x32_bf16(bk1, aq1, t0, 0, 0, 0);
      st_[j] = t0;
    }
    __builtin_amdgcn_s_setprio(0);
    uint32_t pk[8];
    if (domask) {
      const int qrow = qw + lq;
#pragma unroll
      for (int j = 0; j < 4; ++j) {
        float p0 = __builtin_exp2f(st_[j][0]);
        float p1 = __builtin_exp2f(st_[j][1]);
        float p2 = __builtin_exp2f(st_[j][2]);
        float p3 = __builtin_exp2f(st_[j][3]);
        int kvb = kv0 + j * 16 + g * 4;
        p0 = (kvb > qrow) ? 0.f : p0;
        p1 = (kvb + 1 > qrow) ? 0.f : p1;
        p2 = (kvb + 2 > qrow) ? 0.f : p2;
        p3 = (kvb + 3 > qrow) ? 0.f : p3;
        lsum += (p0 + p1) + (p2 + p3);
        pk[2 * j] = cvt_pk_bf16(p0, p1);
        pk[2 * j + 1] = cvt_pk_bf16(p2, p3);
      }
    } else {
#pragma unroll
      for (int j = 0; j < 4; ++j) {
        float p0 = __builtin_exp2f(st_[j][0]);
        float p1 = __builtin_exp2f(st_[j][1]);
        float p2 = __builtin_exp2f(st_[j][2]);
        float p3 = __builtin_exp2f(st_[j][3]);
        lsum += (p0 + p1) + (p2 + p3);
        pk[2 * j] = cvt_pk_bf16(p0, p1);
        pk[2 * j + 1] = cvt_pk_bf16(p2, p3);
      }
    }
#pragma unroll
    for (int j = 0; j < 4; ++j)
      *reinterpret_cast<uint2*>(pw + lq * 128 + ((j * 32 + g * 8) ^ swz)) =
          make_uint2(pk[2 * j], pk[2 * j + 1]);
    bf16x8 pf0 = *reinterpret_cast<const bf16x8*>(pw + fb0);
    bf16x8 pf1 = *reinterpret_cast<const bf16x8*>(pw + fb1);
    __builtin_amdgcn_s_setprio(1);
#pragma unroll
    for (int j2 = 0; j2 < 4; ++j2) {
      bf16x8 v0 = *reinterpret_cast<const bf16x8*>(vb + fb0 + j2 * 2048);
      bf16x8 v1 = *reinterpret_cast<const bf16x8*>(vb + fb1 + j2 * 2048);
      acc[j2] = __builtin_amdgcn_mfma_f32_16x16x32_bf16(v0, pf0, acc[j2], 0, 0, 0);
      acc[j2] = __builtin_amdgcn_mfma_f32_16x16x32_bf16(v1, pf1, acc[j2], 0, 0, 0);
    }
    __builtin_amdgcn_s_setprio(0);
  };

  // prologue: fill ring with tiles st, st+1
  stage(0);
  if (st + 1 < en) {
    stage(1);
    asm volatile("s_waitcnt vmcnt(2)" ::: "memory");   // tile st done; st+1 in flight
  } else {
    WAITVM0;
  }
  __builtin_amdgcn_s_barrier();

  for (int it = st; it < en; ++it) {
    const int idx = it - st;
    if (it + 2 < en) stage((idx + 2) % 3);
    const char* kb = (const char*)K_lds[idx % 3];
    const char* vb = (const char*)V_lds[idx % 3];
    if (!CAUSAL || it <= dtile)                        // wave-uniform skip of masked tiles
      qstep(CAUSAL && it == dtile, it << 6, kb, vb);
    if (it + 2 < en) {
      asm volatile("s_waitcnt vmcnt(2)" ::: "memory"); // tile it+1 done; it+2 in flight
    } else {
      WAITVM0;
    }
    __builtin_amdgcn_s_barrier();
  }

  lsum += __shfl_xor(lsum, 16);
  lsum += __shfl_xor(lsum, 32);
  if constexpr (CAUSAL) {
    u16* OP = (blockIdx.x & 1) ? OP1 : OP0;
    float* Lp = (blockIdx.x & 1) ? L1 : L0;
    const int row = (b * 16 + h) * 2048 + qw + lq;
    u16* pr = OP + (size_t)row * 64;
#pragma unroll
    for (int j2 = 0; j2 < 4; ++j2)
      *reinterpret_cast<uint2*>(pr + j2 * 16 + g * 4) =
          make_uint2(cvt_pk_bf16(acc[j2][0], acc[j2][1]), cvt_pk_bf16(acc[j2][2], acc[j2][3]));
    if (g == 0) Lp[row] = lsum;
  } else {
    float inv = 1.f / lsum;
    size_t rb = qkbase + (size_t)(qw + lq) * 1024;
#pragma unroll
    for (int j2 = 0; j2 < 4; ++j2) {
      ushort4 o = make_ushort4(f2bf(acc[j2][0] * inv), f2bf(acc[j2][1] * inv),
                               f2bf(acc[j2][2] * inv), f2bf(acc[j2][3] * inv));
      *reinterpret_cast<ushort4*>(&O[rb + j2 * 16 + g * 4]) = o;
    }
  }
}

// ---------------- split-K attention merge: O = (O0+O1)/(l0+l1), bf16 -> bf16 [b][q][h*64+dh] ----------------
__global__ __launch_bounds__(256) void k_amrg(const u16* __restrict__ P0, const u16* __restrict__ P1,
                                              const float* __restrict__ L0, const float* __restrict__ L1,
                                              u16* __restrict__ Ab) {
  int i = blockIdx.x * 256 + threadIdx.x;   // 1M threads: [2][16][2048] rows x 16 ushort4
  int row = i >> 4, d4 = (i & 15) << 2;
  ushort4 a4 = *reinterpret_cast<const ushort4*>(&P0[(size_t)row * 64 + d4]);
  ushort4 c4 = *reinterpret_cast<const ushort4*>(&P1[(size_t)row * 64 + d4]);
  float inv = 1.f / (L0[row] + L1[row]);
  int bh = row >> 11, q = row & 2047, bb = bh >> 4, hh = bh & 15;
  size_t dst = ((size_t)(bb * 2048 + q)) * 1024 + hh * 64 + d4;
  ushort4 o = make_ushort4(f2bf((bf2f(a4.x) + bf2f(c4.x)) * inv), f2bf((bf2f(a4.y) + bf2f(c4.y)) * inv),
                           f2bf((bf2f(a4.z) + bf2f(c4.z)) * inv), f2bf((bf2f(a4.w) + bf2f(c4.w)) * inv));
  *reinterpret_cast<ushort4*>(&Ab[dst]) = o;
}

// ---------------- host orchestration ----------------
extern "C" void kernel_launch(void* const* d_in, const int* in_sizes, int n_in,
                              void* d_out, int out_size, void* d_ws, size_t ws_size,
                              hipStream_t stream) {
  const int T = 2048;
  const float* enc = (const float*)d_in[0];
  const float* outv = (const float*)d_in[1];
  auto F = [&](int i) { return (const float*)d_in[i]; };

  size_t off = 0;
  auto alloc = [&](size_t bytes) {
    void* p = (char*)d_ws + off;
    off += (bytes + 255) & ~(size_t)255;
    return p;
  };

  // transposed bf16 weights: q,k,v,o,W1,W2 per tag (q,k,v contiguous -> fused QKV BT)
  const int tdK[12] = {1024, 1024, 1024, 1024, 1024, 2048, 1024, 1024, 1024, 1024, 1024, 2048};
  const int tdM[12] = {1024, 1024, 1024, 1024, 2048, 1024, 1024, 1024, 1024, 1024, 2048, 1024};
  const int tdIdx[12] = {2, 4, 6, 8, 10, 12, 18, 20, 22, 24, 26, 28};
  u16* WT_[12];
  for (int i = 0; i < 12; ++i) WT_[i] = (u16*)alloc((size_t)tdK[i] * tdM[i] * 2);

  u16* Xb0 = (u16*)alloc(4096ull * 1024 * 2);  // bf16(outv): qkv-dd A + LN1 residual
  u16* Eb = (u16*)alloc(4096ull * 1024 * 2);   // bf16(enc)
  u16* Qb = (u16*)alloc(4096ull * 1024 * 2);
  u16* Kb = (u16*)alloc(4096ull * 1024 * 2);
  u16* Vt = (u16*)alloc(4096ull * 1024 * 2);
  u16* Ab = (u16*)alloc(4096ull * 1024 * 2);
  u16* Hb = (u16*)alloc(4096ull * 2048 * 2);   // FFN hidden
  u16* Rm = (u16*)alloc(4096ull * 1024 * 2);   // Oproj/FFN2 bf16 out
  u16* X1b = (u16*)alloc(4096ull * 1024 * 2);  // LN outputs (bf16 residual chain)
  u16* X2b = (u16*)alloc(4096ull * 1024 * 2);
  u16* X3b = (u16*)alloc(4096ull * 1024 * 2);
  u16* OP0 = (u16*)alloc(4096ull * 1024 * 2);  // split-K bf16 partials
  u16* OP1 = (u16*)alloc(4096ull * 1024 * 2);
  float* Lsum = (float*)alloc(2ull * 65536 * 4);

  k_cvt2<<<8192, 256, 0, stream>>>(outv, enc, Xb0, Eb, 4096 * 1024 / 4);

  WTJobs jobs;
  int start = 0;
  for (int i = 0; i < 12; ++i) {
    int msh = (tdM[i] == 2048) ? 6 : 5;
    jobs.j[i] = {F(tdIdx[i]), WT_[i], tdK[i], tdM[i], msh, start};
    start += (tdM[i] >> 5) * (tdK[i] >> 5);
  }
  k_wT_all<<<start, dim3(32, 8), 0, stream>>>(jobs);

  float* L0 = Lsum;
  float* L1 = Lsum + 65536;

  dim3 gq(24, 32);     // fused QKV: N=3072, 128x128 4-wave tiles
  dim3 g1k(16, 32);    // N=1024, JT=2
  dim3 g2k(16, 32);    // FFN1 N=2048, JT=4
  dim3 gac(32, 16, 2); // causal: 16 q-tiles (128 rows) x 2 kv-halves
  dim3 gan(16, 16, 2); // noncausal: 16 q-tiles (128 rows)

  // ---- dd block ----
  k_qkv<<<gq, 256, 0, stream>>>(Xb0, Xb0, WT_[0], F(3), F(5), F(7), Qb, Kb, Vt, 1024);
  k_attn<true><<<gac, 512, 0, stream>>>(Qb, Kb, Vt, Ab, OP0, OP1, L0, L1, T);
  k_amrg<<<4096, 256, 0, stream>>>(OP0, OP1, L0, L1, Ab);
  k_gemm<2, 1><<<g1k, 256, 0, stream>>>(Ab, 1024, WT_[3], F(9), Rm, 1024, 1024);
  k_ln_b<<<4096, 256, 0, stream>>>(Rm, Xb0, F(14), F(15), X1b, nullptr);
  k_gemm<4, 2><<<g2k, 256, 0, stream>>>(X1b, 1024, WT_[4], F(11), Hb, 2048, 1024);
  k_gemm<2, 1><<<g1k, 256, 0, stream>>>(Hb, 2048, WT_[5], F(13), Rm, 1024, 2048);
  k_ln_b<<<4096, 256, 0, stream>>>(Rm, X1b, F(16), F(17), X2b, nullptr);

  // ---- ed block ----
  k_qkv<<<gq, 256, 0, stream>>>(X2b, Eb, WT_[6], F(19), F(21), F(23), Qb, Kb, Vt, 1024);
  k_attn<false><<<gan, 512, 0, stream>>>(Qb, Kb, Vt, Ab, OP0, OP1, L0, L1, T);
  k_gemm<2, 1><<<g1k, 256, 0, stream>>>(Ab, 1024, WT_[9], F(25), Rm, 1024, 1024);
  k_ln_b<<<4096, 256, 0, stream>>>(Rm, X2b, F(30), F(31), X3b, nullptr);
  k_gemm<4, 2><<<g2k, 256, 0, stream>>>(X3b, 1024, WT_[10], F(27), Hb, 2048, 1024);
  k_gemm<2, 1><<<g1k, 256, 0, stream>>>(Hb, 2048, WT_[11], F(29), Rm, 1024, 2048);
  k_ln_b<<<4096, 256, 0, stream>>>(Rm, X3b, F(32), F(33), nullptr, (float*)d_out);
}

// Round 14
// 412.576 us; speedup vs baseline: 1.1851x; 1.0260x over previous
//
#include <hip/hip_runtime.h>
#include <stdint.h>

#define DEV __device__ __forceinline__
typedef unsigned short u16;
typedef __attribute__((ext_vector_type(8))) short bf16x8;
typedef __attribute__((ext_vector_type(4))) float f32x4;

#define AS1 __attribute__((address_space(1)))
#define AS3 __attribute__((address_space(3)))
#define WAITVM0 asm volatile("s_waitcnt vmcnt(0)" ::: "memory")
// scores pre-scaled by 1/sqrt(64) * log2(e) inside the Q-projection epilogue
#define QSCALE 0.18033688011112042f

DEV u16 f2bf(float f) {
  union { float f; uint32_t u; } x; x.f = f;
  uint32_t r = x.u + 0x7fffu + ((x.u >> 16) & 1u);
  return (u16)(r >> 16);
}

DEV float bf2f(u16 h) {
  union { uint32_t u; float f; } x; x.u = ((uint32_t)h) << 16;
  return x.f;
}

DEV uint32_t cvt_pk_bf16(float a, float b) {
  uint32_t r;
  asm("v_cvt_pk_bf16_f32 %0, %1, %2" : "=v"(r) : "v"(a), "v"(b));
  return r;
}

// ---------------- fused init: 12 weight transposes + 2 f32->bf16 converts, one launch ----------------
// Blocks [0, wtBlocks): W f32 [K][M] -> WT bf16 [M][K].  Blocks [wtBlocks, ...): vector cvt.
struct WTJob { const float* W; u16* WT; int K, M, msh, start; };
struct WTJobs { WTJob j[12]; };

__global__ __launch_bounds__(256) void k_init(WTJobs jobs, int wtBlocks,
                                              const float* __restrict__ a, const float* __restrict__ bsrc,
                                              u16* __restrict__ oa, u16* __restrict__ ob, int n4) {
  __shared__ float tile[32][33];
  int b = blockIdx.x;
  int tid = threadIdx.x;
  if (b >= wtBlocks) {
    int i = (b - wtBlocks) * 256 + tid;
    const float* s;
    u16* o;
    int k;
    if (i < n4) { s = a; o = oa; k = i; }
    else        { s = bsrc; o = ob; k = i - n4; }
    float4 v = reinterpret_cast<const float4*>(s)[k];
    reinterpret_cast<ushort4*>(o)[k] = make_ushort4(f2bf(v.x), f2bf(v.y), f2bf(v.z), f2bf(v.w));
    return;
  }
  int i = 0;
#pragma unroll
  for (int t = 1; t < 12; ++t)
    if (b >= jobs.j[t].start) i = t;
  const WTJob J = jobs.j[i];
  int rel = b - J.start;
  int m0 = (rel & ((1 << J.msh) - 1)) << 5;
  int k0 = (rel >> J.msh) << 5;
  int tx = tid & 31, ty = tid >> 5;  // (32,8)
#pragma unroll
  for (int q = 0; q < 4; ++q)
    tile[ty + q * 8][tx] = J.W[(size_t)(k0 + ty + q * 8) * J.M + m0 + tx];
  __syncthreads();
#pragma unroll
  for (int q = 0; q < 4; ++q)
    J.WT[(size_t)(m0 + ty + q * 8) * J.K + k0 + tx] = f2bf(tile[tx][ty + q * 8]);
}

// ---- global->LDS staging of an R x 64 bf16 tile (128B rows), 256 threads ----
template<int R>
DEV void stage_tile(const u16* __restrict__ g, int strideElems, u16* lds, int tid, int wv) {
#pragma unroll
  for (int t = 0; t < R / 32; ++t) {
    int idx = t * 256 + tid;
    int row = idx >> 3;
    int b = (idx & 7) << 4;
    int sb = b ^ ((row & 7) << 4);
    const char* src = (const char*)g + (size_t)row * strideElems * 2 + sb;
    char* dst = (char*)lds + (size_t)(t * 256 + wv * 64) * 16;  // wave-uniform; HW adds lane*16
    __builtin_amdgcn_global_load_lds((const AS1 void*)src, (AS3 void*)dst, 16, 0, 0);
  }
}

// swizzled b128 fragment read from a 64-col bf16 tile
DEV bf16x8 lds_frag(const u16* lds, int row, int kel) {
  int off = row * 128 + ((kel * 2) ^ ((row & 7) << 4));
  return *(const bf16x8*)((const char*)lds + off);
}

// ---------------- GEMM: C[n][m] = A[n][:] . WT[m][:] + bias[m] ----------------
// 128xBN (BN=JT*32), BK=64, 4 waves, 2-stage dbuf, XCD-aware bijective swizzle.
// MODE: 1=bf16 out, 2=bf16 relu out
template<int JT, int MODE>
__global__ __launch_bounds__(256) void k_gemm(const u16* __restrict__ A, int lda,
                                              const u16* __restrict__ BT,
                                              const float* __restrict__ bias,
                                              u16* __restrict__ C, int ldc, int K) {
  constexpr int BN = JT * 32;
  __shared__ __align__(16) u16 A_lds[2][128 * 64];
  __shared__ __align__(16) u16 B_lds[2][BN * 64];
  const int tid = threadIdx.x, lane = tid & 63, wv = tid >> 6;
  const int wm = wv >> 1, wn = wv & 1;
  const int nwg = gridDim.x * gridDim.y;
  const int flat = blockIdx.y * gridDim.x + blockIdx.x;
  const int sw = (flat & 7) * (nwg >> 3) + (flat >> 3);
  const int bx = sw % gridDim.x, by = sw / gridDim.x;
  const int bm0 = by * 128, bn0 = bx * BN;
  const int lr = lane & 15, lk = (lane >> 4) * 8, r0 = (lane >> 4) * 4;

  f32x4 acc[4][JT];
#pragma unroll
  for (int i = 0; i < 4; ++i)
#pragma unroll
    for (int j = 0; j < JT; ++j) acc[i][j] = f32x4{0.f, 0.f, 0.f, 0.f};

  stage_tile<128>(A + (size_t)bm0 * lda, lda, A_lds[0], tid, wv);
  stage_tile<BN>(BT + (size_t)bn0 * K, K, B_lds[0], tid, wv);
  WAITVM0;
  __builtin_amdgcn_s_barrier();

  int cur = 0;
  for (int k0 = 0; k0 < K; k0 += 64) {
    if (k0 + 64 < K) {
      stage_tile<128>(A + (size_t)bm0 * lda + k0 + 64, lda, A_lds[cur ^ 1], tid, wv);
      stage_tile<BN>(BT + (size_t)bn0 * K + k0 + 64, K, B_lds[cur ^ 1], tid, wv);
    }
#pragma unroll
    for (int kk = 0; kk < 2; ++kk) {
      bf16x8 af[4], bfr[JT];
#pragma unroll
      for (int i = 0; i < 4; ++i) af[i] = lds_frag(A_lds[cur], wm * 64 + i * 16 + lr, kk * 32 + lk);
#pragma unroll
      for (int j = 0; j < JT; ++j) bfr[j] = lds_frag(B_lds[cur], wn * (JT * 16) + j * 16 + lr, kk * 32 + lk);
#pragma unroll
      for (int i = 0; i < 4; ++i)
#pragma unroll
        for (int j = 0; j < JT; ++j)
          acc[i][j] = __builtin_amdgcn_mfma_f32_16x16x32_bf16(af[i], bfr[j], acc[i][j], 0, 0, 0);
    }
    WAITVM0;
    __builtin_amdgcn_s_barrier();
    cur ^= 1;
  }

#pragma unroll
  for (int j = 0; j < JT; ++j) {
    int col = bn0 + wn * (JT * 16) + j * 16 + lr;
    float bv = bias[col];
#pragma unroll
    for (int i = 0; i < 4; ++i) {
      int rowb = bm0 + wm * 64 + i * 16 + r0;
#pragma unroll
      for (int r = 0; r < 4; ++r) {
        float v = acc[i][j][r] + bv;
        if constexpr (MODE == 2) v = fmaxf(v, 0.f);
        C[(size_t)(rowb + r) * ldc + col] = f2bf(v);
      }
    }
  }
}

// ---------------- fused QKV projection: 128x128 tile (4 waves, 64x64/wave), N=3072 ----------------
__global__ __launch_bounds__(256) void k_qkv(const u16* __restrict__ Aq, const u16* __restrict__ Akv,
                                             const u16* __restrict__ BT,
                                             const float* __restrict__ bq, const float* __restrict__ bk,
                                             const float* __restrict__ bv,
                                             u16* __restrict__ Qb, u16* __restrict__ Kb,
                                             u16* __restrict__ Vt, int K) {
  __shared__ __align__(16) u16 A_lds[2][128 * 64];
  __shared__ __align__(16) u16 B_lds[2][128 * 64];
  const int tid = threadIdx.x, lane = tid & 63, wv = tid >> 6;
  const int wm = wv >> 1, wn = wv & 1;
  const int nwg = gridDim.x * gridDim.y;
  const int flat = blockIdx.y * gridDim.x + blockIdx.x;
  const int sw = (flat & 7) * (nwg >> 3) + (flat >> 3);
  const int bx = sw % gridDim.x, by = sw / gridDim.x;
  const int bm0 = by * 128, bn0 = bx * 128;
  const int seg = bn0 >> 10;
  const u16* A = (seg == 0) ? Aq : Akv;
  const int lr = lane & 15, lk = (lane >> 4) * 8, r0 = (lane >> 4) * 4;

  f32x4 acc[4][4];
#pragma unroll
  for (int i = 0; i < 4; ++i)
#pragma unroll
    for (int j = 0; j < 4; ++j) acc[i][j] = f32x4{0.f, 0.f, 0.f, 0.f};

  stage_tile<128>(A + (size_t)bm0 * K, K, A_lds[0], tid, wv);
  stage_tile<128>(BT + (size_t)bn0 * K, K, B_lds[0], tid, wv);
  WAITVM0;
  __builtin_amdgcn_s_barrier();

  int cur = 0;
  for (int k0 = 0; k0 < K; k0 += 64) {
    if (k0 + 64 < K) {
      stage_tile<128>(A + (size_t)bm0 * K + k0 + 64, K, A_lds[cur ^ 1], tid, wv);
      stage_tile<128>(BT + (size_t)bn0 * K + k0 + 64, K, B_lds[cur ^ 1], tid, wv);
    }
#pragma unroll
    for (int kk = 0; kk < 2; ++kk) {
      bf16x8 af[4], bfr[4];
#pragma unroll
      for (int i = 0; i < 4; ++i) af[i] = lds_frag(A_lds[cur], wm * 64 + i * 16 + lr, kk * 32 + lk);
#pragma unroll
      for (int j = 0; j < 4; ++j) bfr[j] = lds_frag(B_lds[cur], wn * 64 + j * 16 + lr, kk * 32 + lk);
#pragma unroll
      for (int i = 0; i < 4; ++i)
#pragma unroll
        for (int j = 0; j < 4; ++j)
          acc[i][j] = __builtin_amdgcn_mfma_f32_16x16x32_bf16(af[i], bfr[j], acc[i][j], 0, 0, 0);
    }
    WAITVM0;
    __builtin_amdgcn_s_barrier();
    cur ^= 1;
  }

#pragma unroll
  for (int j = 0; j < 4; ++j) {
    int col = bn0 + wn * 64 + j * 16 + lr;
    int cl = col & 1023;
#pragma unroll
    for (int i = 0; i < 4; ++i) {
      int rowb = bm0 + wm * 64 + i * 16 + r0;
      if (seg == 0) {
        float bb = bq[cl];
#pragma unroll
        for (int r = 0; r < 4; ++r)
          Qb[(size_t)(rowb + r) * 1024 + cl] = f2bf((acc[i][j][r] + bb) * QSCALE);
      } else if (seg == 1) {
        float bb = bk[cl];
#pragma unroll
        for (int r = 0; r < 4; ++r)
          Kb[(size_t)(rowb + r) * 1024 + cl] = f2bf(acc[i][j][r] + bb);
      } else {
        float bb = bv[cl];
        int bidx = rowb >> 11, t = rowb & 2047;
        ushort4 o = make_ushort4(f2bf(acc[i][j][0] + bb), f2bf(acc[i][j][1] + bb),
                                 f2bf(acc[i][j][2] + bb), f2bf(acc[i][j][3] + bb));
        *reinterpret_cast<ushort4*>(&Vt[((size_t)bidx * 1024 + cl) * 2048 + t]) = o;
      }
    }
  }
}

// ---------------- fused residual LayerNorm, all-bf16 dataflow ----------------
__global__ __launch_bounds__(256) void k_ln_b(const u16* __restrict__ Rm, const u16* __restrict__ X,
                                              const float* __restrict__ g, const float* __restrict__ be,
                                              u16* __restrict__ Yb, float* __restrict__ Yf) {
  int row = blockIdx.x;
  size_t base4 = (size_t)row * 256;
  int t = threadIdx.x;
  ushort4 a4 = reinterpret_cast<const ushort4*>(Rm)[base4 + t];
  ushort4 x4 = reinterpret_cast<const ushort4*>(X)[base4 + t];
  float v0 = bf2f(a4.x) + bf2f(x4.x), v1 = bf2f(a4.y) + bf2f(x4.y);
  float v2 = bf2f(a4.z) + bf2f(x4.z), v3 = bf2f(a4.w) + bf2f(x4.w);
  float s = v0 + v1 + v2 + v3;
  float ss = v0 * v0 + v1 * v1 + v2 * v2 + v3 * v3;
#pragma unroll
  for (int m = 1; m < 64; m <<= 1) { s += __shfl_xor(s, m); ss += __shfl_xor(ss, m); }
  __shared__ float red[8];
  int wv = t >> 6;
  if ((t & 63) == 0) { red[wv] = s; red[4 + wv] = ss; }
  __syncthreads();
  s = red[0] + red[1] + red[2] + red[3];
  ss = red[4] + red[5] + red[6] + red[7];
  float mean = s * (1.f / 1024.f);
  float var = ss * (1.f / 1024.f) - mean * mean;
  float rstd = rsqrtf(var + 1e-5f);
  float4 gv = reinterpret_cast<const float4*>(g)[t];
  float4 bv = reinterpret_cast<const float4*>(be)[t];
  float o0 = (v0 - mean) * rstd * gv.x + bv.x;
  float o1 = (v1 - mean) * rstd * gv.y + bv.y;
  float o2 = (v2 - mean) * rstd * gv.z + bv.z;
  float o3 = (v3 - mean) * rstd * gv.w + bv.w;
  if (Yb) {
    ushort4 ob = make_ushort4(f2bf(o0), f2bf(o1), f2bf(o2), f2bf(o3));
    reinterpret_cast<ushort4*>(Yb)[base4 + t] = ob;
  }
  if (Yf)
    reinterpret_cast<float4*>(Yf)[base4 + t] = make_float4(o0, o1, o2, o3);
}

// ---------------- flash attention: 8 waves, QBLK=128, 3-buffer ring, counted vmcnt ----------------
// Direct bf16 output for both variants. Causal: heavy-first q-tile order, per-wave diagonal skip
// (split-K dropped: makespan is set by the longest block's step count in every arrangement,
// so partial-write+merge traffic was pure overhead).
template<bool CAUSAL>
__global__ __launch_bounds__(512) void k_attn(const u16* __restrict__ Q, const u16* __restrict__ Kg,
                                              const u16* __restrict__ Vt, u16* __restrict__ O, int T) {
  __shared__ __align__(16) u16 K_lds[3][64 * 64];
  __shared__ __align__(16) u16 V_lds[3][64 * 64];   // V^T tiles: [dh][kv]
  __shared__ __align__(16) u16 p_lds[8][16 * 64];   // per-wave P rows, swizzled
  const int tid = threadIdx.x, lane = tid & 63, wv = tid >> 6;
  const int h = blockIdx.y, b = blockIdx.z;
  const int lq = lane & 15, g = lane >> 4;
  const int swz = (lq & 7) << 4;
  const int fb0 = lq * 128 + ((g * 16) ^ swz);
  const int fb1 = lq * 128 + ((g * 16 + 64) ^ swz);
  const size_t qkbase = ((size_t)b * T) * 1024 + h * 64;
  const size_t vbase = ((size_t)b * 1024 + h * 64) * T;

  const int qx = CAUSAL ? (gridDim.x - 1 - blockIdx.x) : blockIdx.x;  // heavy first
  const int en = CAUSAL ? (2 * qx + 2) : (T >> 6);
  const int qw = qx * 128 + wv * 16;
  const int dtile = qw >> 6;                    // this wave's diagonal kv-tile

  bf16x8 aq0, aq1;
  {
    const u16* qp_ = Q + qkbase + (size_t)(qw + lq) * 1024 + g * 8;
    aq0 = *reinterpret_cast<const bf16x8*>(qp_);
    aq1 = *reinterpret_cast<const bf16x8*>(qp_ + 32);
  }

  // staging: 512 threads, 1 K-load + 1 V-load each (16B), pre-swizzled source
  const int srow = tid >> 3;
  const int ssb = ((tid & 7) << 4) ^ ((srow & 7) << 4);
  const char* ksrc = (const char*)(Kg + qkbase) + (size_t)srow * 2048 + ssb;
  const char* vsrc = (const char*)(Vt + vbase) + (size_t)srow * ((size_t)T * 2) + ssb;
  const uint32_t doff = (uint32_t)(wv << 10);   // wave-uniform LDS base; HW adds lane*16

  auto stage = [&](int buf) {
    __builtin_amdgcn_global_load_lds((const AS1 void*)ksrc, (AS3 void*)((char*)K_lds[buf] + doff), 16, 0, 0);
    __builtin_amdgcn_global_load_lds((const AS1 void*)vsrc, (AS3 void*)((char*)V_lds[buf] + doff), 16, 0, 0);
    ksrc += 131072;   // 64 rows * 2048B
    vsrc += 128;      // 64 kv cols * 2B
  };

  f32x4 acc[4];
  float lsum = 0.f;
#pragma unroll
  for (int j = 0; j < 4; ++j) acc[j] = f32x4{0.f, 0.f, 0.f, 0.f};

  char* pw = (char*)p_lds[wv];

  auto qstep = [&](bool domask, int kv0, const char* kb, const char* vb) {
    f32x4 st_[4];
    __builtin_amdgcn_s_setprio(1);
#pragma unroll
    for (int j = 0; j < 4; ++j) {
      bf16x8 bk0 = *reinterpret_cast<const bf16x8*>(kb + fb0 + j * 2048);
      bf16x8 bk1 = *reinterpret_cast<const bf16x8*>(kb + fb1 + j * 2048);
      f32x4 t0 = f32x4{0.f, 0.f, 0.f, 0.f};
      t0 = __builtin_amdgcn_mfma_f32_16x16x32_bf16(bk0, aq0, t0, 0, 0, 0);
      t0 = __builtin_amdgcn_mfma_f32_16x16x32_bf16(bk1, aq1, t0, 0, 0, 0);
      st_[j] = t0;
    }
    __builtin_amdgcn_s_setprio(0);
    uint32_t pk[8];
    if (domask) {
      const int qrow = qw + lq;
#pragma unroll
      for (int j = 0; j < 4; ++j) {
        float p0 = __builtin_exp2f(st_[j][0]);
        float p1 = __builtin_exp2f(st_[j][1]);
        float p2 = __builtin_exp2f(st_[j][2]);
        float p3 = __builtin_exp2f(st_[j][3]);
        int kvb = kv0 + j * 16 + g * 4;
        p0 = (kvb > qrow) ? 0.f : p0;
        p1 = (kvb + 1 > qrow) ? 0.f : p1;
        p2 = (kvb + 2 > qrow) ? 0.f : p2;
        p3 = (kvb + 3 > qrow) ? 0.f : p3;
        lsum += (p0 + p1) + (p2 + p3);
        pk[2 * j] = cvt_pk_bf16(p0, p1);
        pk[2 * j + 1] = cvt_pk_bf16(p2, p3);
      }
    } else {
#pragma unroll
      for (int j = 0; j < 4; ++j) {
        float p0 = __builtin_exp2f(st_[j][0]);
        float p1 = __builtin_exp2f(st_[j][1]);
        float p2 = __builtin_exp2f(st_[j][2]);
        float p3 = __builtin_exp2f(st_[j][3]);
        lsum += (p0 + p1) + (p2 + p3);
        pk[2 * j] = cvt_pk_bf16(p0, p1);
        pk[2 * j + 1] = cvt_pk_bf16(p2, p3);
      }
    }
#pragma unroll
    for (int j = 0; j < 4; ++j)
      *reinterpret_cast<uint2*>(pw + lq * 128 + ((j * 32 + g * 8) ^ swz)) =
          make_uint2(pk[2 * j], pk[2 * j + 1]);
    bf16x8 pf0 = *reinterpret_cast<const bf16x8*>(pw + fb0);
    bf16x8 pf1 = *reinterpret_cast<const bf16x8*>(pw + fb1);
    __builtin_amdgcn_s_setprio(1);
#pragma unroll
    for (int j2 = 0; j2 < 4; ++j2) {
      bf16x8 v0 = *reinterpret_cast<const bf16x8*>(vb + fb0 + j2 * 2048);
      bf16x8 v1 = *reinterpret_cast<const bf16x8*>(vb + fb1 + j2 * 2048);
      acc[j2] = __builtin_amdgcn_mfma_f32_16x16x32_bf16(v0, pf0, acc[j2], 0, 0, 0);
      acc[j2] = __builtin_amdgcn_mfma_f32_16x16x32_bf16(v1, pf1, acc[j2], 0, 0, 0);
    }
    __builtin_amdgcn_s_setprio(0);
  };

  // prologue: fill ring with tiles 0, 1
  stage(0);
  if (en > 1) {
    stage(1);
    asm volatile("s_waitcnt vmcnt(2)" ::: "memory");   // tile 0 done; tile 1 in flight
  } else {
    WAITVM0;
  }
  __builtin_amdgcn_s_barrier();

  for (int it = 0; it < en; ++it) {
    if (it + 2 < en) stage((it + 2) % 3);
    const char* kb = (const char*)K_lds[it % 3];
    const char* vb = (const char*)V_lds[it % 3];
    if (!CAUSAL || it <= dtile)                        // wave-uniform skip of masked tiles
      qstep(CAUSAL && it == dtile, it << 6, kb, vb);
    if (it + 2 < en) {
      asm volatile("s_waitcnt vmcnt(2)" ::: "memory"); // tile it+1 done; it+2 in flight
    } else {
      WAITVM0;
    }
    __builtin_amdgcn_s_barrier();
  }

  lsum += __shfl_xor(lsum, 16);
  lsum += __shfl_xor(lsum, 32);
  float inv = 1.f / lsum;
  size_t rb = qkbase + (size_t)(qw + lq) * 1024;
#pragma unroll
  for (int j2 = 0; j2 < 4; ++j2) {
    ushort4 o = make_ushort4(f2bf(acc[j2][0] * inv), f2bf(acc[j2][1] * inv),
                             f2bf(acc[j2][2] * inv), f2bf(acc[j2][3] * inv));
    *reinterpret_cast<ushort4*>(&O[rb + j2 * 16 + g * 4]) = o;
  }
}

// ---------------- host orchestration ----------------
extern "C" void kernel_launch(void* const* d_in, const int* in_sizes, int n_in,
                              void* d_out, int out_size, void* d_ws, size_t ws_size,
                              hipStream_t stream) {
  const int T = 2048;
  const float* enc = (const float*)d_in[0];
  const float* outv = (const float*)d_in[1];
  auto F = [&](int i) { return (const float*)d_in[i]; };

  size_t off = 0;
  auto alloc = [&](size_t bytes) {
    void* p = (char*)d_ws + off;
    off += (bytes + 255) & ~(size_t)255;
    return p;
  };

  // transposed bf16 weights: q,k,v,o,W1,W2 per tag (q,k,v contiguous -> fused QKV BT)
  const int tdK[12] = {1024, 1024, 1024, 1024, 1024, 2048, 1024, 1024, 1024, 1024, 1024, 2048};
  const int tdM[12] = {1024, 1024, 1024, 1024, 2048, 1024, 1024, 1024, 1024, 1024, 2048, 1024};
  const int tdIdx[12] = {2, 4, 6, 8, 10, 12, 18, 20, 22, 24, 26, 28};
  u16* WT_[12];
  for (int i = 0; i < 12; ++i) WT_[i] = (u16*)alloc((size_t)tdK[i] * tdM[i] * 2);

  u16* Xb0 = (u16*)alloc(4096ull * 1024 * 2);  // bf16(outv): qkv-dd A + LN1 residual
  u16* Eb = (u16*)alloc(4096ull * 1024 * 2);   // bf16(enc)
  u16* Qb = (u16*)alloc(4096ull * 1024 * 2);
  u16* Kb = (u16*)alloc(4096ull * 1024 * 2);
  u16* Vt = (u16*)alloc(4096ull * 1024 * 2);
  u16* Ab = (u16*)alloc(4096ull * 1024 * 2);
  u16* Hb = (u16*)alloc(4096ull * 2048 * 2);   // FFN hidden
  u16* Rm = (u16*)alloc(4096ull * 1024 * 2);   // Oproj/FFN2 bf16 out
  u16* X1b = (u16*)alloc(4096ull * 1024 * 2);  // LN outputs (bf16 residual chain)
  u16* X2b = (u16*)alloc(4096ull * 1024 * 2);
  u16* X3b = (u16*)alloc(4096ull * 1024 * 2);

  // fused init: 12 transposes + both converts in one launch
  WTJobs jobs;
  int start = 0;
  for (int i = 0; i < 12; ++i) {
    int msh = (tdM[i] == 2048) ? 6 : 5;
    jobs.j[i] = {F(tdIdx[i]), WT_[i], tdK[i], tdM[i], msh, start};
    start += (tdM[i] >> 5) * (tdK[i] >> 5);
  }
  const int n4 = 4096 * 1024 / 4;
  k_init<<<start + 8192, 256, 0, stream>>>(jobs, start, outv, enc, Xb0, Eb, n4);

  dim3 gq(24, 32);     // fused QKV: N=3072, 128x128 4-wave tiles
  dim3 g1k(16, 32);    // N=1024, JT=2
  dim3 g2k(16, 32);    // FFN1 N=2048, JT=4
  dim3 ga(16, 16, 2);  // attn: 16 q-tiles (128 rows)

  // ---- dd block ----
  k_qkv<<<gq, 256, 0, stream>>>(Xb0, Xb0, WT_[0], F(3), F(5), F(7), Qb, Kb, Vt, 1024);
  k_attn<true><<<ga, 512, 0, stream>>>(Qb, Kb, Vt, Ab, T);
  k_gemm<2, 1><<<g1k, 256, 0, stream>>>(Ab, 1024, WT_[3], F(9), Rm, 1024, 1024);
  k_ln_b<<<4096, 256, 0, stream>>>(Rm, Xb0, F(14), F(15), X1b, nullptr);
  k_gemm<4, 2><<<g2k, 256, 0, stream>>>(X1b, 1024, WT_[4], F(11), Hb, 2048, 1024);
  k_gemm<2, 1><<<g1k, 256, 0, stream>>>(Hb, 2048, WT_[5], F(13), Rm, 1024, 2048);
  k_ln_b<<<4096, 256, 0, stream>>>(Rm, X1b, F(16), F(17), X2b, nullptr);

  // ---- ed block ----
  k_qkv<<<gq, 256, 0, stream>>>(X2b, Eb, WT_[6], F(19), F(21), F(23), Qb, Kb, Vt, 1024);
  k_attn<false><<<ga, 512, 0, stream>>>(Qb, Kb, Vt, Ab, T);
  k_gemm<2, 1><<<g1k, 256, 0, stream>>>(Ab, 1024, WT_[9], F(25), Rm, 1024, 1024);
  k_ln_b<<<4096, 256, 0, stream>>>(Rm, X2b, F(30), F(31), X3b, nullptr);
  k_gemm<4, 2><<<g2k, 256, 0, stream>>>(X3b, 1024, WT_[10], F(27), Hb, 2048, 1024);
  k_gemm<2, 1><<<g1k, 256, 0, stream>>>(Hb, 2048, WT_[11], F(29), Rm, 1024, 2048);
  k_ln_b<<<4096, 256, 0, stream>>>(Rm, X3b, F(32), F(33), nullptr, (float*)d_out);
}

// Round 15
// 396.917 us; speedup vs baseline: 1.2319x; 1.0395x over previous
//
#include <hip/hip_runtime.h>
#include <stdint.h>

#define DEV __device__ __forceinline__
typedef unsigned short u16;
typedef __attribute__((ext_vector_type(8))) short bf16x8;
typedef __attribute__((ext_vector_type(4))) float f32x4;

#define AS1 __attribute__((address_space(1)))
#define AS3 __attribute__((address_space(3)))
#define WAITVM0 asm volatile("s_waitcnt vmcnt(0)" ::: "memory")
// scores pre-scaled by 1/sqrt(64) * log2(e) inside the Q-projection epilogue
#define QSCALE 0.18033688011112042f

DEV u16 f2bf(float f) {
  union { float f; uint32_t u; } x; x.f = f;
  uint32_t r = x.u + 0x7fffu + ((x.u >> 16) & 1u);
  return (u16)(r >> 16);
}

DEV float bf2f(u16 h) {
  union { uint32_t u; float f; } x; x.u = ((uint32_t)h) << 16;
  return x.f;
}

DEV uint32_t cvt_pk_bf16(float a, float b) {
  uint32_t r;
  asm("v_cvt_pk_bf16_f32 %0, %1, %2" : "=v"(r) : "v"(a), "v"(b));
  return r;
}

// ---------------- fused init: 12 weight transposes + 2 f32->bf16 converts, one launch ----------------
struct WTJob { const float* W; u16* WT; int K, M, msh, start; };
struct WTJobs { WTJob j[12]; };

__global__ __launch_bounds__(256) void k_init(WTJobs jobs, int wtBlocks,
                                              const float* __restrict__ a, const float* __restrict__ bsrc,
                                              u16* __restrict__ oa, u16* __restrict__ ob, int n4) {
  __shared__ float tile[32][33];
  int b = blockIdx.x;
  int tid = threadIdx.x;
  if (b >= wtBlocks) {
    int i = (b - wtBlocks) * 256 + tid;
    const float* s;
    u16* o;
    int k;
    if (i < n4) { s = a; o = oa; k = i; }
    else        { s = bsrc; o = ob; k = i - n4; }
    float4 v = reinterpret_cast<const float4*>(s)[k];
    reinterpret_cast<ushort4*>(o)[k] = make_ushort4(f2bf(v.x), f2bf(v.y), f2bf(v.z), f2bf(v.w));
    return;
  }
  int i = 0;
#pragma unroll
  for (int t = 1; t < 12; ++t)
    if (b >= jobs.j[t].start) i = t;
  const WTJob J = jobs.j[i];
  int rel = b - J.start;
  int m0 = (rel & ((1 << J.msh) - 1)) << 5;
  int k0 = (rel >> J.msh) << 5;
  int tx = tid & 31, ty = tid >> 5;  // (32,8)
#pragma unroll
  for (int q = 0; q < 4; ++q)
    tile[ty + q * 8][tx] = J.W[(size_t)(k0 + ty + q * 8) * J.M + m0 + tx];
  __syncthreads();
#pragma unroll
  for (int q = 0; q < 4; ++q)
    J.WT[(size_t)(m0 + ty + q * 8) * J.K + k0 + tx] = f2bf(tile[tx][ty + q * 8]);
}

// ---- global->LDS staging of an R x 64 bf16 tile (128B rows), 256 threads ----
template<int R>
DEV void stage_tile(const u16* __restrict__ g, int strideElems, u16* lds, int tid, int wv) {
#pragma unroll
  for (int t = 0; t < R / 32; ++t) {
    int idx = t * 256 + tid;
    int row = idx >> 3;
    int b = (idx & 7) << 4;
    int sb = b ^ ((row & 7) << 4);
    const char* src = (const char*)g + (size_t)row * strideElems * 2 + sb;
    char* dst = (char*)lds + (size_t)(t * 256 + wv * 64) * 16;  // wave-uniform; HW adds lane*16
    __builtin_amdgcn_global_load_lds((const AS1 void*)src, (AS3 void*)dst, 16, 0, 0);
  }
}

// ---- global->LDS staging of an R x 64 bf16 tile, 512 threads ----
template<int R>
DEV void stage512(const u16* __restrict__ g, int strideElems, u16* lds, int tid, int wv) {
#pragma unroll
  for (int t = 0; t < R / 64; ++t) {
    int idx = t * 512 + tid;
    int row = idx >> 3;
    int b = (idx & 7) << 4;
    int sb = b ^ ((row & 7) << 4);
    const char* src = (const char*)g + (size_t)row * strideElems * 2 + sb;
    char* dst = (char*)lds + (size_t)(t * 512 + wv * 64) * 16;
    __builtin_amdgcn_global_load_lds((const AS1 void*)src, (AS3 void*)dst, 16, 0, 0);
  }
}

// swizzled b128 fragment read from a 64-col bf16 tile
DEV bf16x8 lds_frag(const u16* lds, int row, int kel) {
  int off = row * 128 + ((kel * 2) ^ ((row & 7) << 4));
  return *(const bf16x8*)((const char*)lds + off);
}

// ---------------- GEMM: C[n][m] = A[n][:] . WT[m][:] + bias[m] ----------------
// 128xBN (BN=JT*32), BK=64, 4 waves, 2-stage dbuf, XCD-aware bijective swizzle.
// MODE: 1=bf16 out, 2=bf16 relu out, 3=bf16 scaled (QSCALE) out
template<int JT, int MODE>
__global__ __launch_bounds__(256) void k_gemm(const u16* __restrict__ A, int lda,
                                              const u16* __restrict__ BT,
                                              const float* __restrict__ bias,
                                              u16* __restrict__ C, int ldc, int K) {
  constexpr int BN = JT * 32;
  __shared__ __align__(16) u16 A_lds[2][128 * 64];
  __shared__ __align__(16) u16 B_lds[2][BN * 64];
  const int tid = threadIdx.x, lane = tid & 63, wv = tid >> 6;
  const int wm = wv >> 1, wn = wv & 1;
  const int nwg = gridDim.x * gridDim.y;
  const int flat = blockIdx.y * gridDim.x + blockIdx.x;
  const int sw = (flat & 7) * (nwg >> 3) + (flat >> 3);
  const int bx = sw % gridDim.x, by = sw / gridDim.x;
  const int bm0 = by * 128, bn0 = bx * BN;
  const int lr = lane & 15, lk = (lane >> 4) * 8, r0 = (lane >> 4) * 4;

  f32x4 acc[4][JT];
#pragma unroll
  for (int i = 0; i < 4; ++i)
#pragma unroll
    for (int j = 0; j < JT; ++j) acc[i][j] = f32x4{0.f, 0.f, 0.f, 0.f};

  stage_tile<128>(A + (size_t)bm0 * lda, lda, A_lds[0], tid, wv);
  stage_tile<BN>(BT + (size_t)bn0 * K, K, B_lds[0], tid, wv);
  WAITVM0;
  __builtin_amdgcn_s_barrier();

  int cur = 0;
  for (int k0 = 0; k0 < K; k0 += 64) {
    if (k0 + 64 < K) {
      stage_tile<128>(A + (size_t)bm0 * lda + k0 + 64, lda, A_lds[cur ^ 1], tid, wv);
      stage_tile<BN>(BT + (size_t)bn0 * K + k0 + 64, K, B_lds[cur ^ 1], tid, wv);
    }
#pragma unroll
    for (int kk = 0; kk < 2; ++kk) {
      bf16x8 af[4], bfr[JT];
#pragma unroll
      for (int i = 0; i < 4; ++i) af[i] = lds_frag(A_lds[cur], wm * 64 + i * 16 + lr, kk * 32 + lk);
#pragma unroll
      for (int j = 0; j < JT; ++j) bfr[j] = lds_frag(B_lds[cur], wn * (JT * 16) + j * 16 + lr, kk * 32 + lk);
#pragma unroll
      for (int i = 0; i < 4; ++i)
#pragma unroll
        for (int j = 0; j < JT; ++j)
          acc[i][j] = __builtin_amdgcn_mfma_f32_16x16x32_bf16(af[i], bfr[j], acc[i][j], 0, 0, 0);
    }
    WAITVM0;
    __builtin_amdgcn_s_barrier();
    cur ^= 1;
  }

#pragma unroll
  for (int j = 0; j < JT; ++j) {
    int col = bn0 + wn * (JT * 16) + j * 16 + lr;
    float bv = bias[col];
#pragma unroll
    for (int i = 0; i < 4; ++i) {
      int rowb = bm0 + wm * 64 + i * 16 + r0;
#pragma unroll
      for (int r = 0; r < 4; ++r) {
        float v = acc[i][j][r] + bv;
        if constexpr (MODE == 2) v = fmaxf(v, 0.f);
        if constexpr (MODE == 3) v = v * QSCALE;
        C[(size_t)(rowb + r) * ldc + col] = f2bf(v);
      }
    }
  }
}

// ---------------- fused QKV projection: 128x128 tile (4 waves, 64x64/wave), N=3072 ----------------
__global__ __launch_bounds__(256) void k_qkv(const u16* __restrict__ Aq, const u16* __restrict__ Akv,
                                             const u16* __restrict__ BT,
                                             const float* __restrict__ bq, const float* __restrict__ bk,
                                             const float* __restrict__ bv,
                                             u16* __restrict__ Qb, u16* __restrict__ Kb,
                                             u16* __restrict__ Vt, int K) {
  __shared__ __align__(16) u16 A_lds[2][128 * 64];
  __shared__ __align__(16) u16 B_lds[2][128 * 64];
  const int tid = threadIdx.x, lane = tid & 63, wv = tid >> 6;
  const int wm = wv >> 1, wn = wv & 1;
  const int nwg = gridDim.x * gridDim.y;
  const int flat = blockIdx.y * gridDim.x + blockIdx.x;
  const int sw = (flat & 7) * (nwg >> 3) + (flat >> 3);
  const int bx = sw % gridDim.x, by = sw / gridDim.x;
  const int bm0 = by * 128, bn0 = bx * 128;
  const int seg = bn0 >> 10;
  const u16* A = (seg == 0) ? Aq : Akv;
  const int lr = lane & 15, lk = (lane >> 4) * 8, r0 = (lane >> 4) * 4;

  f32x4 acc[4][4];
#pragma unroll
  for (int i = 0; i < 4; ++i)
#pragma unroll
    for (int j = 0; j < 4; ++j) acc[i][j] = f32x4{0.f, 0.f, 0.f, 0.f};

  stage_tile<128>(A + (size_t)bm0 * K, K, A_lds[0], tid, wv);
  stage_tile<128>(BT + (size_t)bn0 * K, K, B_lds[0], tid, wv);
  WAITVM0;
  __builtin_amdgcn_s_barrier();

  int cur = 0;
  for (int k0 = 0; k0 < K; k0 += 64) {
    if (k0 + 64 < K) {
      stage_tile<128>(A + (size_t)bm0 * K + k0 + 64, K, A_lds[cur ^ 1], tid, wv);
      stage_tile<128>(BT + (size_t)bn0 * K + k0 + 64, K, B_lds[cur ^ 1], tid, wv);
    }
#pragma unroll
    for (int kk = 0; kk < 2; ++kk) {
      bf16x8 af[4], bfr[4];
#pragma unroll
      for (int i = 0; i < 4; ++i) af[i] = lds_frag(A_lds[cur], wm * 64 + i * 16 + lr, kk * 32 + lk);
#pragma unroll
      for (int j = 0; j < 4; ++j) bfr[j] = lds_frag(B_lds[cur], wn * 64 + j * 16 + lr, kk * 32 + lk);
#pragma unroll
      for (int i = 0; i < 4; ++i)
#pragma unroll
        for (int j = 0; j < 4; ++j)
          acc[i][j] = __builtin_amdgcn_mfma_f32_16x16x32_bf16(af[i], bfr[j], acc[i][j], 0, 0, 0);
    }
    WAITVM0;
    __builtin_amdgcn_s_barrier();
    cur ^= 1;
  }

#pragma unroll
  for (int j = 0; j < 4; ++j) {
    int col = bn0 + wn * 64 + j * 16 + lr;
    int cl = col & 1023;
#pragma unroll
    for (int i = 0; i < 4; ++i) {
      int rowb = bm0 + wm * 64 + i * 16 + r0;
      if (seg == 0) {
        float bb = bq[cl];
#pragma unroll
        for (int r = 0; r < 4; ++r)
          Qb[(size_t)(rowb + r) * 1024 + cl] = f2bf((acc[i][j][r] + bb) * QSCALE);
      } else if (seg == 1) {
        float bb = bk[cl];
#pragma unroll
        for (int r = 0; r < 4; ++r)
          Kb[(size_t)(rowb + r) * 1024 + cl] = f2bf(acc[i][j][r] + bb);
      } else {
        float bb = bv[cl];
        int bidx = rowb >> 11, t = rowb & 2047;
        ushort4 o = make_ushort4(f2bf(acc[i][j][0] + bb), f2bf(acc[i][j][1] + bb),
                                 f2bf(acc[i][j][2] + bb), f2bf(acc[i][j][3] + bb));
        *reinterpret_cast<ushort4*>(&Vt[((size_t)bidx * 1024 + cl) * 2048 + t]) = o;
      }
    }
  }
}

// ---------------- fused residual LayerNorm, all-bf16 dataflow ----------------
__global__ __launch_bounds__(256) void k_ln_b(const u16* __restrict__ Rm, const u16* __restrict__ X,
                                              const float* __restrict__ g, const float* __restrict__ be,
                                              u16* __restrict__ Yb, float* __restrict__ Yf) {
  int row = blockIdx.x;
  size_t base4 = (size_t)row * 256;
  int t = threadIdx.x;
  ushort4 a4 = reinterpret_cast<const ushort4*>(Rm)[base4 + t];
  ushort4 x4 = reinterpret_cast<const ushort4*>(X)[base4 + t];
  float v0 = bf2f(a4.x) + bf2f(x4.x), v1 = bf2f(a4.y) + bf2f(x4.y);
  float v2 = bf2f(a4.z) + bf2f(x4.z), v3 = bf2f(a4.w) + bf2f(x4.w);
  float s = v0 + v1 + v2 + v3;
  float ss = v0 * v0 + v1 * v1 + v2 * v2 + v3 * v3;
#pragma unroll
  for (int m = 1; m < 64; m <<= 1) { s += __shfl_xor(s, m); ss += __shfl_xor(ss, m); }
  __shared__ float red[8];
  int wv = t >> 6;
  if ((t & 63) == 0) { red[wv] = s; red[4 + wv] = ss; }
  __syncthreads();
  s = red[0] + red[1] + red[2] + red[3];
  ss = red[4] + red[5] + red[6] + red[7];
  float mean = s * (1.f / 1024.f);
  float var = ss * (1.f / 1024.f) - mean * mean;
  float rstd = rsqrtf(var + 1e-5f);
  float4 gv = reinterpret_cast<const float4*>(g)[t];
  float4 bv = reinterpret_cast<const float4*>(be)[t];
  float o0 = (v0 - mean) * rstd * gv.x + bv.x;
  float o1 = (v1 - mean) * rstd * gv.y + bv.y;
  float o2 = (v2 - mean) * rstd * gv.z + bv.z;
  float o3 = (v3 - mean) * rstd * gv.w + bv.w;
  if (Yb) {
    ushort4 ob = make_ushort4(f2bf(o0), f2bf(o1), f2bf(o2), f2bf(o3));
    reinterpret_cast<ushort4*>(Yb)[base4 + t] = ob;
  }
  if (Yf)
    reinterpret_cast<float4*>(Yf)[base4 + t] = make_float4(o0, o1, o2, o3);
}

// ---------------- flash attention (standalone, noncausal ed): R14-proven ----------------
template<bool CAUSAL>
__global__ __launch_bounds__(512) void k_attn(const u16* __restrict__ Q, const u16* __restrict__ Kg,
                                              const u16* __restrict__ Vt, u16* __restrict__ O, int T) {
  __shared__ __align__(16) u16 K_lds[3][64 * 64];
  __shared__ __align__(16) u16 V_lds[3][64 * 64];
  __shared__ __align__(16) u16 p_lds[8][16 * 64];
  const int tid = threadIdx.x, lane = tid & 63, wv = tid >> 6;
  const int h = blockIdx.y, b = blockIdx.z;
  const int lq = lane & 15, g = lane >> 4;
  const int swz = (lq & 7) << 4;
  const int fb0 = lq * 128 + ((g * 16) ^ swz);
  const int fb1 = lq * 128 + ((g * 16 + 64) ^ swz);
  const size_t qkbase = ((size_t)b * T) * 1024 + h * 64;
  const size_t vbase = ((size_t)b * 1024 + h * 64) * T;

  const int qx = CAUSAL ? (gridDim.x - 1 - blockIdx.x) : blockIdx.x;
  const int en = CAUSAL ? (2 * qx + 2) : (T >> 6);
  const int qw = qx * 128 + wv * 16;
  const int dtile = qw >> 6;

  bf16x8 aq0, aq1;
  {
    const u16* qp_ = Q + qkbase + (size_t)(qw + lq) * 1024 + g * 8;
    aq0 = *reinterpret_cast<const bf16x8*>(qp_);
    aq1 = *reinterpret_cast<const bf16x8*>(qp_ + 32);
  }

  const int srow = tid >> 3;
  const int ssb = ((tid & 7) << 4) ^ ((srow & 7) << 4);
  const char* ksrc = (const char*)(Kg + qkbase) + (size_t)srow * 2048 + ssb;
  const char* vsrc = (const char*)(Vt + vbase) + (size_t)srow * ((size_t)T * 2) + ssb;
  const uint32_t doff = (uint32_t)(wv << 10);

  auto stage = [&](int buf) {
    __builtin_amdgcn_global_load_lds((const AS1 void*)ksrc, (AS3 void*)((char*)K_lds[buf] + doff), 16, 0, 0);
    __builtin_amdgcn_global_load_lds((const AS1 void*)vsrc, (AS3 void*)((char*)V_lds[buf] + doff), 16, 0, 0);
    ksrc += 131072;
    vsrc += 128;
  };

  f32x4 acc[4];
  float lsum = 0.f;
#pragma unroll
  for (int j = 0; j < 4; ++j) acc[j] = f32x4{0.f, 0.f, 0.f, 0.f};

  char* pw = (char*)p_lds[wv];

  auto qstep = [&](bool domask, int kv0, const char* kb, const char* vb) {
    f32x4 st_[4];
    __builtin_amdgcn_s_setprio(1);
#pragma unroll
    for (int j = 0; j < 4; ++j) {
      bf16x8 bk0 = *reinterpret_cast<const bf16x8*>(kb + fb0 + j * 2048);
      bf16x8 bk1 = *reinterpret_cast<const bf16x8*>(kb + fb1 + j * 2048);
      f32x4 t0 = f32x4{0.f, 0.f, 0.f, 0.f};
      t0 = __builtin_amdgcn_mfma_f32_16x16x32_bf16(bk0, aq0, t0, 0, 0, 0);
      t0 = __builtin_amdgcn_mfma_f32_16x16x32_bf16(bk1, aq1, t0, 0, 0, 0);
      st_[j] = t0;
    }
    __builtin_amdgcn_s_setprio(0);
    uint32_t pk[8];
    if (domask) {
      const int qrow = qw + lq;
#pragma unroll
      for (int j = 0; j < 4; ++j) {
        float p0 = __builtin_exp2f(st_[j][0]);
        float p1 = __builtin_exp2f(st_[j][1]);
        float p2 = __builtin_exp2f(st_[j][2]);
        float p3 = __builtin_exp2f(st_[j][3]);
        int kvb = kv0 + j * 16 + g * 4;
        p0 = (kvb > qrow) ? 0.f : p0;
        p1 = (kvb + 1 > qrow) ? 0.f : p1;
        p2 = (kvb + 2 > qrow) ? 0.f : p2;
        p3 = (kvb + 3 > qrow) ? 0.f : p3;
        lsum += (p0 + p1) + (p2 + p3);
        pk[2 * j] = cvt_pk_bf16(p0, p1);
        pk[2 * j + 1] = cvt_pk_bf16(p2, p3);
      }
    } else {
#pragma unroll
      for (int j = 0; j < 4; ++j) {
        float p0 = __builtin_exp2f(st_[j][0]);
        float p1 = __builtin_exp2f(st_[j][1]);
        float p2 = __builtin_exp2f(st_[j][2]);
        float p3 = __builtin_exp2f(st_[j][3]);
        lsum += (p0 + p1) + (p2 + p3);
        pk[2 * j] = cvt_pk_bf16(p0, p1);
        pk[2 * j + 1] = cvt_pk_bf16(p2, p3);
      }
    }
#pragma unroll
    for (int j = 0; j < 4; ++j)
      *reinterpret_cast<uint2*>(pw + lq * 128 + ((j * 32 + g * 8) ^ swz)) =
          make_uint2(pk[2 * j], pk[2 * j + 1]);
    bf16x8 pf0 = *reinterpret_cast<const bf16x8*>(pw + fb0);
    bf16x8 pf1 = *reinterpret_cast<const bf16x8*>(pw + fb1);
    __builtin_amdgcn_s_setprio(1);
#pragma unroll
    for (int j2 = 0; j2 < 4; ++j2) {
      bf16x8 v0 = *reinterpret_cast<const bf16x8*>(vb + fb0 + j2 * 2048);
      bf16x8 v1 = *reinterpret_cast<const bf16x8*>(vb + fb1 + j2 * 2048);
      acc[j2] = __builtin_amdgcn_mfma_f32_16x16x32_bf16(v0, pf0, acc[j2], 0, 0, 0);
      acc[j2] = __builtin_amdgcn_mfma_f32_16x16x32_bf16(v1, pf1, acc[j2], 0, 0, 0);
    }
    __builtin_amdgcn_s_setprio(0);
  };

  stage(0);
  if (en > 1) {
    stage(1);
    asm volatile("s_waitcnt vmcnt(2)" ::: "memory");
  } else {
    WAITVM0;
  }
  __builtin_amdgcn_s_barrier();

  for (int it = 0; it < en; ++it) {
    if (it + 2 < en) stage((it + 2) % 3);
    const char* kb = (const char*)K_lds[it % 3];
    const char* vb = (const char*)V_lds[it % 3];
    if (!CAUSAL || it <= dtile)
      qstep(CAUSAL && it == dtile, it << 6, kb, vb);
    if (it + 2 < en) {
      asm volatile("s_waitcnt vmcnt(2)" ::: "memory");
    } else {
      WAITVM0;
    }
    __builtin_amdgcn_s_barrier();
  }

  lsum += __shfl_xor(lsum, 16);
  lsum += __shfl_xor(lsum, 32);
  float inv = 1.f / lsum;
  size_t rb = qkbase + (size_t)(qw + lq) * 1024;
#pragma unroll
  for (int j2 = 0; j2 < 4; ++j2) {
    ushort4 o = make_ushort4(f2bf(acc[j2][0] * inv), f2bf(acc[j2][1] * inv),
                             f2bf(acc[j2][2] * inv), f2bf(acc[j2][3] * inv));
    *reinterpret_cast<ushort4*>(&O[rb + j2 * 16 + g * 4]) = o;
  }
}

// ---------------- MERGED: causal attn (blocks 0..511) + ed K/V projection (blocks 512..1023) ----------------
// Fills causal attn's idle pipes (20% Mfma, 53% VALU) with the independent enc->K/V GEMM.
// Shared LDS = max(attn 64KB, gemm 80KB) = 80KB -> 2 blocks/CU for both.
__global__ __launch_bounds__(512) void k_attn_kv(const u16* __restrict__ Q, const u16* __restrict__ Kg,
                                                 const u16* __restrict__ Vt, u16* __restrict__ O, int T,
                                                 const u16* __restrict__ Eb, const u16* __restrict__ BT2,
                                                 const float* __restrict__ bk2, const float* __restrict__ bv2,
                                                 u16* __restrict__ Kb2, u16* __restrict__ Vt2) {
  __shared__ __align__(16) char smem[81920];
  const int tid = threadIdx.x, lane = tid & 63, wv = tid >> 6;

  if (blockIdx.x < 512) {
    // ======== causal flash attention (R14-proven structure) ========
    const int a = blockIdx.x;
    const int b = a >> 8, h = (a >> 4) & 15, qi = a & 15;
    const int qx = 15 - qi;  // heavy q-tiles first
    const int en = 2 * qx + 2;
    const int lq = lane & 15, g = lane >> 4;
    const int swz = (lq & 7) << 4;
    const int fb0 = lq * 128 + ((g * 16) ^ swz);
    const int fb1 = lq * 128 + ((g * 16 + 64) ^ swz);
    const size_t qkbase = ((size_t)b * T) * 1024 + h * 64;
    const size_t vbase = ((size_t)b * 1024 + h * 64) * T;
    const int qw = qx * 128 + wv * 16;
    const int dtile = qw >> 6;

    char* Kl = smem;               // 3 x 8KB
    char* Vl = smem + 24576;       // 3 x 8KB
    char* pw = smem + 49152 + (wv << 11);  // 8 x 2KB

    bf16x8 aq0, aq1;
    {
      const u16* qp_ = Q + qkbase + (size_t)(qw + lq) * 1024 + g * 8;
      aq0 = *reinterpret_cast<const bf16x8*>(qp_);
      aq1 = *reinterpret_cast<const bf16x8*>(qp_ + 32);
    }

    const int srow = tid >> 3;
    const int ssb = ((tid & 7) << 4) ^ ((srow & 7) << 4);
    const char* ksrc = (const char*)(Kg + qkbase) + (size_t)srow * 2048 + ssb;
    const char* vsrc = (const char*)(Vt + vbase) + (size_t)srow * ((size_t)T * 2) + ssb;
    const uint32_t doff = (uint32_t)(wv << 10);

    auto stage = [&](int buf) {
      __builtin_amdgcn_global_load_lds((const AS1 void*)ksrc, (AS3 void*)(Kl + buf * 8192 + doff), 16, 0, 0);
      __builtin_amdgcn_global_load_lds((const AS1 void*)vsrc, (AS3 void*)(Vl + buf * 8192 + doff), 16, 0, 0);
      ksrc += 131072;
      vsrc += 128;
    };

    f32x4 acc[4];
    float lsum = 0.f;
#pragma unroll
    for (int j = 0; j < 4; ++j) acc[j] = f32x4{0.f, 0.f, 0.f, 0.f};

    auto qstep = [&](bool domask, int kv0, const char* kb, const char* vb) {
      f32x4 st_[4];
      __builtin_amdgcn_s_setprio(1);
#pragma unroll
      for (int j = 0; j < 4; ++j) {
        bf16x8 bk0 = *reinterpret_cast<const bf16x8*>(kb + fb0 + j * 2048);
        bf16x8 bk1 = *reinterpret_cast<const bf16x8*>(kb + fb1 + j * 2048);
        f32x4 t0 = f32x4{0.f, 0.f, 0.f, 0.f};
        t0 = __builtin_amdgcn_mfma_f32_16x16x32_bf16(bk0, aq0, t0, 0, 0, 0);
        t0 = __builtin_amdgcn_mfma_f32_16x16x32_bf16(bk1, aq1, t0, 0, 0, 0);
        st_[j] = t0;
      }
      __builtin_amdgcn_s_setprio(0);
      uint32_t pk[8];
      if (domask) {
        const int qrow = qw + lq;
#pragma unroll
        for (int j = 0; j < 4; ++j) {
          float p0 = __builtin_exp2f(st_[j][0]);
          float p1 = __builtin_exp2f(st_[j][1]);
          float p2 = __builtin_exp2f(st_[j][2]);
          float p3 = __builtin_exp2f(st_[j][3]);
          int kvb = kv0 + j * 16 + g * 4;
          p0 = (kvb > qrow) ? 0.f : p0;
          p1 = (kvb + 1 > qrow) ? 0.f : p1;
          p2 = (kvb + 2 > qrow) ? 0.f : p2;
          p3 = (kvb + 3 > qrow) ? 0.f : p3;
          lsum += (p0 + p1) + (p2 + p3);
          pk[2 * j] = cvt_pk_bf16(p0, p1);
          pk[2 * j + 1] = cvt_pk_bf16(p2, p3);
        }
      } else {
#pragma unroll
        for (int j = 0; j < 4; ++j) {
          float p0 = __builtin_exp2f(st_[j][0]);
          float p1 = __builtin_exp2f(st_[j][1]);
          float p2 = __builtin_exp2f(st_[j][2]);
          float p3 = __builtin_exp2f(st_[j][3]);
          lsum += (p0 + p1) + (p2 + p3);
          pk[2 * j] = cvt_pk_bf16(p0, p1);
          pk[2 * j + 1] = cvt_pk_bf16(p2, p3);
        }
      }
#pragma unroll
      for (int j = 0; j < 4; ++j)
        *reinterpret_cast<uint2*>(pw + lq * 128 + ((j * 32 + g * 8) ^ swz)) =
            make_uint2(pk[2 * j], pk[2 * j + 1]);
      bf16x8 pf0 = *reinterpret_cast<const bf16x8*>(pw + fb0);
      bf16x8 pf1 = *reinterpret_cast<const bf16x8*>(pw + fb1);
      __builtin_amdgcn_s_setprio(1);
#pragma unroll
      for (int j2 = 0; j2 < 4; ++j2) {
        bf16x8 v0 = *reinterpret_cast<const bf16x8*>(vb + fb0 + j2 * 2048);
        bf16x8 v1 = *reinterpret_cast<const bf16x8*>(vb + fb1 + j2 * 2048);
        acc[j2] = __builtin_amdgcn_mfma_f32_16x16x32_bf16(v0, pf0, acc[j2], 0, 0, 0);
        acc[j2] = __builtin_amdgcn_mfma_f32_16x16x32_bf16(v1, pf1, acc[j2], 0, 0, 0);
      }
      __builtin_amdgcn_s_setprio(0);
    };

    stage(0);
    if (en > 1) {
      stage(1);
      asm volatile("s_waitcnt vmcnt(2)" ::: "memory");
    } else {
      WAITVM0;
    }
    __builtin_amdgcn_s_barrier();

    for (int it = 0; it < en; ++it) {
      if (it + 2 < en) stage((it + 2) % 3);
      const char* kb = Kl + (it % 3) * 8192;
      const char* vb = Vl + (it % 3) * 8192;
      if (it <= dtile)
        qstep(it == dtile, it << 6, kb, vb);
      if (it + 2 < en) {
        asm volatile("s_waitcnt vmcnt(2)" ::: "memory");
      } else {
        WAITVM0;
      }
      __builtin_amdgcn_s_barrier();
    }

    lsum += __shfl_xor(lsum, 16);
    lsum += __shfl_xor(lsum, 32);
    float inv = 1.f / lsum;
    size_t rb = qkbase + (size_t)(qw + lq) * 1024;
#pragma unroll
    for (int j2 = 0; j2 < 4; ++j2) {
      ushort4 o = make_ushort4(f2bf(acc[j2][0] * inv), f2bf(acc[j2][1] * inv),
                               f2bf(acc[j2][2] * inv), f2bf(acc[j2][3] * inv));
      *reinterpret_cast<ushort4*>(&O[rb + j2 * 16 + g * 4]) = o;
    }
  } else {
    // ======== ed K/V projection filler: 256x64 tile, 8 waves (4Mx2N) ========
    const int g2 = blockIdx.x - 512;
    const int bx = g2 & 31, by = g2 >> 5;
    const int bm0 = by * 256, bn0 = bx * 64;
    const int wm = wv >> 1, wn = wv & 1;
    const int lr = lane & 15, lk = (lane >> 4) * 8, r0 = (lane >> 4) * 4;
    u16* A_lds = (u16*)smem;            // 2 x 32KB
    u16* B_lds = (u16*)(smem + 65536);  // 2 x 8KB
    const int K = 1024;

    f32x4 acc[4][2];
#pragma unroll
    for (int i = 0; i < 4; ++i)
#pragma unroll
      for (int j = 0; j < 2; ++j) acc[i][j] = f32x4{0.f, 0.f, 0.f, 0.f};

    stage512<256>(Eb + (size_t)bm0 * K, K, A_lds, tid, wv);
    stage512<64>(BT2 + (size_t)bn0 * K, K, B_lds, tid, wv);
    WAITVM0;
    __builtin_amdgcn_s_barrier();

    int cur = 0;
    for (int k0 = 0; k0 < K; k0 += 64) {
      if (k0 + 64 < K) {
        stage512<256>(Eb + (size_t)bm0 * K + k0 + 64, K, A_lds + (cur ^ 1) * 256 * 64, tid, wv);
        stage512<64>(BT2 + (size_t)bn0 * K + k0 + 64, K, B_lds + (cur ^ 1) * 64 * 64, tid, wv);
      }
#pragma unroll
      for (int kk = 0; kk < 2; ++kk) {
        bf16x8 af[4], bfr[2];
#pragma unroll
        for (int i = 0; i < 4; ++i)
          af[i] = lds_frag(A_lds + cur * 256 * 64, wm * 64 + i * 16 + lr, kk * 32 + lk);
#pragma unroll
        for (int j = 0; j < 2; ++j)
          bfr[j] = lds_frag(B_lds + cur * 64 * 64, wn * 32 + j * 16 + lr, kk * 32 + lk);
#pragma unroll
        for (int i = 0; i < 4; ++i)
#pragma unroll
          for (int j = 0; j < 2; ++j)
            acc[i][j] = __builtin_amdgcn_mfma_f32_16x16x32_bf16(af[i], bfr[j], acc[i][j], 0, 0, 0);
      }
      WAITVM0;
      __builtin_amdgcn_s_barrier();
      cur ^= 1;
    }

#pragma unroll
    for (int j = 0; j < 2; ++j) {
      int col = bn0 + wn * 32 + j * 16 + lr;
#pragma unroll
      for (int i = 0; i < 4; ++i) {
        int rowb = bm0 + wm * 64 + i * 16 + r0;
        if (col < 1024) {
          float bb = bk2[col];
#pragma unroll
          for (int r = 0; r < 4; ++r)
            Kb2[(size_t)(rowb + r) * 1024 + col] = f2bf(acc[i][j][r] + bb);
        } else {
          int cl = col - 1024;
          float bb = bv2[cl];
          int bidx = rowb >> 11, t = rowb & 2047;
          ushort4 o = make_ushort4(f2bf(acc[i][j][0] + bb), f2bf(acc[i][j][1] + bb),
                                   f2bf(acc[i][j][2] + bb), f2bf(acc[i][j][3] + bb));
          *reinterpret_cast<ushort4*>(&Vt2[((size_t)bidx * 1024 + cl) * 2048 + t]) = o;
        }
      }
    }
  }
}

// ---------------- host orchestration ----------------
extern "C" void kernel_launch(void* const* d_in, const int* in_sizes, int n_in,
                              void* d_out, int out_size, void* d_ws, size_t ws_size,
                              hipStream_t stream) {
  const int T = 2048;
  const float* enc = (const float*)d_in[0];
  const float* outv = (const float*)d_in[1];
  auto F = [&](int i) { return (const float*)d_in[i]; };

  size_t off = 0;
  auto alloc = [&](size_t bytes) {
    void* p = (char*)d_ws + off;
    off += (bytes + 255) & ~(size_t)255;
    return p;
  };

  // transposed bf16 weights: q,k,v,o,W1,W2 per tag (q,k,v contiguous; WT_[7]/WT_[8] contiguous for KV filler)
  const int tdK[12] = {1024, 1024, 1024, 1024, 1024, 2048, 1024, 1024, 1024, 1024, 1024, 2048};
  const int tdM[12] = {1024, 1024, 1024, 1024, 2048, 1024, 1024, 1024, 1024, 1024, 2048, 1024};
  const int tdIdx[12] = {2, 4, 6, 8, 10, 12, 18, 20, 22, 24, 26, 28};
  u16* WT_[12];
  for (int i = 0; i < 12; ++i) WT_[i] = (u16*)alloc((size_t)tdK[i] * tdM[i] * 2);

  u16* Xb0 = (u16*)alloc(4096ull * 1024 * 2);  // bf16(outv)
  u16* Eb = (u16*)alloc(4096ull * 1024 * 2);   // bf16(enc)
  u16* Qb = (u16*)alloc(4096ull * 1024 * 2);
  u16* Kb = (u16*)alloc(4096ull * 1024 * 2);
  u16* Vt = (u16*)alloc(4096ull * 1024 * 2);
  u16* Qb2 = (u16*)alloc(4096ull * 1024 * 2);  // ed Q
  u16* Kb2 = (u16*)alloc(4096ull * 1024 * 2);  // ed K (from merged launch)
  u16* Vt2 = (u16*)alloc(4096ull * 1024 * 2);  // ed V^T (from merged launch)
  u16* Ab = (u16*)alloc(4096ull * 1024 * 2);
  u16* Hb = (u16*)alloc(4096ull * 2048 * 2);
  u16* Rm = (u16*)alloc(4096ull * 1024 * 2);
  u16* X1b = (u16*)alloc(4096ull * 1024 * 2);
  u16* X2b = (u16*)alloc(4096ull * 1024 * 2);
  u16* X3b = (u16*)alloc(4096ull * 1024 * 2);

  // fused init: 12 transposes + both converts in one launch
  WTJobs jobs;
  int start = 0;
  for (int i = 0; i < 12; ++i) {
    int msh = (tdM[i] == 2048) ? 6 : 5;
    jobs.j[i] = {F(tdIdx[i]), WT_[i], tdK[i], tdM[i], msh, start};
    start += (tdM[i] >> 5) * (tdK[i] >> 5);
  }
  const int n4 = 4096 * 1024 / 4;
  k_init<<<start + 8192, 256, 0, stream>>>(jobs, start, outv, enc, Xb0, Eb, n4);

  dim3 gq(24, 32);     // fused QKV dd: N=3072, 128x128 4-wave tiles
  dim3 g1k(16, 32);    // N=1024, JT=2
  dim3 g2k(16, 32);    // FFN1 N=2048, JT=4
  dim3 ga(16, 16, 2);  // noncausal attn: 16 q-tiles (128 rows)

  // ---- dd block ----
  k_qkv<<<gq, 256, 0, stream>>>(Xb0, Xb0, WT_[0], F(3), F(5), F(7), Qb, Kb, Vt, 1024);
  // causal attn (dd) overlapped with independent ed K/V projection
  k_attn_kv<<<1024, 512, 0, stream>>>(Qb, Kb, Vt, Ab, T, Eb, WT_[7], F(21), F(23), Kb2, Vt2);
  k_gemm<2, 1><<<g1k, 256, 0, stream>>>(Ab, 1024, WT_[3], F(9), Rm, 1024, 1024);
  k_ln_b<<<4096, 256, 0, stream>>>(Rm, Xb0, F(14), F(15), X1b, nullptr);
  k_gemm<4, 2><<<g2k, 256, 0, stream>>>(X1b, 1024, WT_[4], F(11), Hb, 2048, 1024);
  k_gemm<2, 1><<<g1k, 256, 0, stream>>>(Hb, 2048, WT_[5], F(13), Rm, 1024, 2048);
  k_ln_b<<<4096, 256, 0, stream>>>(Rm, X1b, F(16), F(17), X2b, nullptr);

  // ---- ed block ----
  k_gemm<2, 3><<<g1k, 256, 0, stream>>>(X2b, 1024, WT_[6], F(19), Qb2, 1024, 1024);  // Q only
  k_attn<false><<<ga, 512, 0, stream>>>(Qb2, Kb2, Vt2, Ab, T);
  k_gemm<2, 1><<<g1k, 256, 0, stream>>>(Ab, 1024, WT_[9], F(25), Rm, 1024, 1024);
  k_ln_b<<<4096, 256, 0, stream>>>(Rm, X2b, F(30), F(31), X3b, nullptr);
  k_gemm<4, 2><<<g2k, 256, 0, stream>>>(X3b, 1024, WT_[10], F(27), Hb, 2048, 1024);
  k_gemm<2, 1><<<g1k, 256, 0, stream>>>(Hb, 2048, WT_[11], F(29), Rm, 1024, 2048);
  k_ln_b<<<4096, 256, 0, stream>>>(Rm, X3b, F(32), F(33), nullptr, (float*)d_out);
}